// Round 1
// 440.592 us; speedup vs baseline: 1.7914x; 1.7914x over previous
//
#include <hip/hip_runtime.h>
#include <hip/hip_bf16.h>

#define B_ 4
#define L_ 3136
#define D_ 256
#define NCH 49     // 49 chunks * 64 = 3136
#define LCH 64
#define M_ (B_*L_)

__device__ __forceinline__ float bf2f(unsigned short u) {
    union { unsigned int i; float f; } v; v.i = ((unsigned int)u) << 16; return v.f;
}
__device__ __forceinline__ unsigned short f2bs(float f) {
    __hip_bfloat16 h = __float2bfloat16(f);
    return *(unsigned short*)&h;
}
// dual-dtype load for INPUT tensors (bf16 if flag, else fp32)
__device__ __forceinline__ float ldw(const void* p, size_t i, bool bf) {
    return bf ? bf2f(((const unsigned short*)p)[i]) : ((const float*)p)[i];
}

// ------------------------------------------------- dtype detection
__global__ __launch_bounds__(256) void detect_kernel(
    const unsigned int* __restrict__ xw, int* __restrict__ flag)
{
    int t = threadIdx.x; int cnt = 0;
    for (int i = t; i < 2048; i += 256) {
        unsigned int lo = xw[i] & 0xFFFFu;
        unsigned int e = (lo >> 7) & 0xFFu;
        if (e >= 0x58u && e <= 0x97u) cnt++;
    }
    #pragma unroll
    for (int o = 32; o > 0; o >>= 1) cnt += __shfl_down(cnt, o);
    __shared__ int sred[4];
    if ((t & 63) == 0) sred[t >> 6] = cnt;
    __syncthreads();
    if (t == 0) flag[0] = (sred[0] + sred[1] + sred[2] + sred[3] > 1024) ? 1 : 0;
}

// ------------------------------------------------- LayerNorm -> bf16 out
__global__ __launch_bounds__(256) void ln_kernel(
    const void* __restrict__ xin, int inmode,   // -1: dual via flag; 1: bf16
    const void* __restrict__ g, const void* __restrict__ bsh,
    unsigned short* __restrict__ out, const int* __restrict__ flagp)
{
    const bool wbf = (*flagp != 0);
    const bool inbf = (inmode < 0) ? wbf : true;
    int row = blockIdx.x, t = threadIdx.x;
    size_t idx = (size_t)row * 256 + t;
    float v = inbf ? bf2f(((const unsigned short*)xin)[idx]) : ((const float*)xin)[idx];
    float s = v, s2 = v * v;
    #pragma unroll
    for (int o = 32; o > 0; o >>= 1) { s += __shfl_down(s, o); s2 += __shfl_down(s2, o); }
    __shared__ float red[8];
    int w = t >> 6;
    if ((t & 63) == 0) { red[w] = s; red[4 + w] = s2; }
    __syncthreads();
    float S  = red[0] + red[1] + red[2] + red[3];
    float S2 = red[4] + red[5] + red[6] + red[7];
    float mean = S * (1.f / 256.f);
    float var  = S2 * (1.f / 256.f) - mean * mean;
    float rs = rsqrtf(var + 1e-5f);
    out[idx] = f2bs((v - mean) * rs * ldw(g, t, wbf) + ldw(bsh, t, wbf));
}

// ------------------------------------------------- epilogue tags
enum { EPI_NONE = 0, EPI_SP = 1, EPI_RES = 2, EPI_GELU = 3, EPI_OUT = 4 };

// ------------------------------------------------- MFMA bf16 GEMM
// C[M,N] = A[M,K](bf16) * W[N,K]^T.  M,N multiples of 128.  BK=32.
// 256 threads = 4 waves in 2x2; each wave: 64x64 via 4x4 frags of 16x16x32.
typedef __attribute__((ext_vector_type(8))) short bf16x8;
typedef __attribute__((ext_vector_type(4))) float f32x4;

__device__ __forceinline__ void gload_lds16(const void* g, void* l) {
    __builtin_amdgcn_global_load_lds(
        (const __attribute__((address_space(1))) unsigned int*)g,
        (__attribute__((address_space(3))) unsigned int*)l, 16, 0, 0);
}

template<int EPI>
__global__ __launch_bounds__(256) void mgemm_kernel(
    const unsigned short* __restrict__ A, const unsigned short* __restrict__ A2, int Ksplit,
    const void* __restrict__ W, void* __restrict__ Cout,
    int N, int K, int lda, int ldc,
    const void* __restrict__ bias, const void* __restrict__ resb,
    const unsigned short* __restrict__ resf, const int* __restrict__ flagp)
{
    const bool wbf = (*flagp != 0);
    __shared__ unsigned short As[128][32];
    __shared__ unsigned short Ws[128][32];
    const int tid = threadIdx.x;
    const int bm = blockIdx.y * 128, bn = blockIdx.x * 128;
    const int l = tid & 63, wid = tid >> 6;
    const int wr = wid >> 1, wc = wid & 1;
    const int lr = l & 15;            // row within A-frag / col within B-frag
    const int lk = (l >> 4) * 8;      // k-offset group within BK=32
    const int srow = tid >> 2;        // staging row 0..63
    const int scol = (tid & 3) * 8;   // staging k-offset

    f32x4 acc[4][4] = {};

    for (int k0 = 0; k0 < K; k0 += 32) {
        // --- stage A tile (always bf16) via async global->LDS, width 16
        const unsigned short* Ab; int kc;
        if (k0 < Ksplit) { Ab = A;  kc = k0; }
        else             { Ab = A2; kc = k0 - Ksplit; }
        gload_lds16(Ab + (size_t)(bm + srow) * lda + kc + scol,       &As[srow][scol]);
        gload_lds16(Ab + (size_t)(bm + 64 + srow) * lda + kc + scol,  &As[64 + srow][scol]);
        // --- stage W tile
        if (wbf) {
            const unsigned short* Wb = (const unsigned short*)W;
            gload_lds16(Wb + (size_t)(bn + srow) * K + k0 + scol,      &Ws[srow][scol]);
            gload_lds16(Wb + (size_t)(bn + 64 + srow) * K + k0 + scol, &Ws[64 + srow][scol]);
        } else {
            const float* Wf = (const float*)W;
            #pragma unroll
            for (int h = 0; h < 2; ++h) {
                const float* p = Wf + (size_t)(bn + h * 64 + srow) * K + k0 + scol;
                float4 w0 = *(const float4*)p;
                float4 w1 = *(const float4*)(p + 4);
                ushort4 o0, o1;
                o0.x = f2bs(w0.x); o0.y = f2bs(w0.y); o0.z = f2bs(w0.z); o0.w = f2bs(w0.w);
                o1.x = f2bs(w1.x); o1.y = f2bs(w1.y); o1.z = f2bs(w1.z); o1.w = f2bs(w1.w);
                *(ushort4*)&Ws[h * 64 + srow][scol]     = o0;
                *(ushort4*)&Ws[h * 64 + srow][scol + 4] = o1;
            }
        }
        asm volatile("s_waitcnt vmcnt(0)" ::: "memory");
        __syncthreads();

        bf16x8 af[4], bfr[4];
        #pragma unroll
        for (int i = 0; i < 4; ++i) {
            af[i]  = *(const bf16x8*)&As[wr * 64 + i * 16 + lr][lk];
            bfr[i] = *(const bf16x8*)&Ws[wc * 64 + i * 16 + lr][lk];
        }
        #pragma unroll
        for (int i = 0; i < 4; ++i)
            #pragma unroll
            for (int j = 0; j < 4; ++j)
                acc[i][j] = __builtin_amdgcn_mfma_f32_16x16x32_bf16(af[i], bfr[j], acc[i][j], 0, 0, 0);
        __syncthreads();
    }

    // epilogue: lane l elem e -> row (l>>4)*4+e, col l&15 of each 16x16 frag
    #pragma unroll
    for (int i = 0; i < 4; ++i) {
        #pragma unroll
        for (int j = 0; j < 4; ++j) {
            const int col = bn + wc * 64 + j * 16 + lr;
            #pragma unroll
            for (int e = 0; e < 4; ++e) {
                const int row = bm + wr * 64 + i * 16 + (l >> 4) * 4 + e;
                float t = acc[i][j][e];
                if (EPI == EPI_RES) {
                    t += ldw(resb, (size_t)row * 256 + col, wbf);
                } else if (EPI == EPI_GELU) {
                    t += ldw(bias, col, wbf);
                    t = 0.5f * t * (1.f + erff(t * 0.70710678118654752f));
                } else if (EPI == EPI_OUT) {
                    t += ldw(bias, col, wbf) + bf2f(resf[(size_t)row * 256 + col]);
                }
                if (EPI == EPI_OUT && !wbf) {
                    ((float*)Cout)[(size_t)row * ldc + col] = t;
                } else {
                    ((unsigned short*)Cout)[(size_t)row * ldc + col] = f2bs(t);
                }
            }
        }
    }
}

// ------------------------------------------------- small fp32 GEMM (x_proj, dt_proj)
template<int EPI, bool ABF, bool CBF>
__global__ __launch_bounds__(256) void gemm_kernel(
    const void* __restrict__ A, const void* __restrict__ A2, int Ksplit,
    const void* __restrict__ W, void* __restrict__ Cout,
    int N, int K, int lda, int ldc,
    const void* __restrict__ bias, const void* __restrict__ resb,
    const unsigned short* __restrict__ resf, const int* __restrict__ flagp)
{
    const bool wbf = (*flagp != 0);
    __shared__ float As[16][132];
    __shared__ float Ws[16][132];
    const int tid = threadIdx.x;
    const int bm = blockIdx.y * 128, bn = blockIdx.x * 128;
    const int tx = tid & 15, ty = tid >> 4;
    const int lrow = tid >> 1;
    const int lk = (tid & 1) * 8;

    float acc[8][8];
    #pragma unroll
    for (int i = 0; i < 8; ++i)
        #pragma unroll
        for (int j = 0; j < 8; ++j) acc[i][j] = 0.f;

    for (int k0 = 0; k0 < K; k0 += 16) {
        float av[8];
        if (ABF) {
            const unsigned short* Ab; int kc;
            if (k0 < Ksplit) { Ab = (const unsigned short*)A;  kc = k0; }
            else             { Ab = (const unsigned short*)A2; kc = k0 - Ksplit; }
            const unsigned short* Ap = Ab + (size_t)(bm + lrow) * lda + kc + lk;
            ushort4 a0 = *(const ushort4*)Ap;
            ushort4 a1 = *(const ushort4*)(Ap + 4);
            av[0] = bf2f(a0.x); av[1] = bf2f(a0.y); av[2] = bf2f(a0.z); av[3] = bf2f(a0.w);
            av[4] = bf2f(a1.x); av[5] = bf2f(a1.y); av[6] = bf2f(a1.z); av[7] = bf2f(a1.w);
        } else {
            const float* Ap = (const float*)A + (size_t)(bm + lrow) * lda + k0 + lk;
            float4 a0 = *(const float4*)Ap;
            float4 a1 = *(const float4*)(Ap + 4);
            av[0] = a0.x; av[1] = a0.y; av[2] = a0.z; av[3] = a0.w;
            av[4] = a1.x; av[5] = a1.y; av[6] = a1.z; av[7] = a1.w;
        }
        #pragma unroll
        for (int j = 0; j < 8; ++j) As[lk + j][lrow] = av[j];

        int n = bn + lrow;
        float wv[8];
        #pragma unroll
        for (int j = 0; j < 8; ++j) wv[j] = 0.f;
        if (n < N) {
            if (wbf) {
                const unsigned short* Wp = (const unsigned short*)W + (size_t)n * K + k0 + lk;
                ushort4 w0 = *(const ushort4*)Wp;
                ushort4 w1 = *(const ushort4*)(Wp + 4);
                wv[0] = bf2f(w0.x); wv[1] = bf2f(w0.y); wv[2] = bf2f(w0.z); wv[3] = bf2f(w0.w);
                wv[4] = bf2f(w1.x); wv[5] = bf2f(w1.y); wv[6] = bf2f(w1.z); wv[7] = bf2f(w1.w);
            } else {
                const float* Wp = (const float*)W + (size_t)n * K + k0 + lk;
                float4 w0 = *(const float4*)Wp;
                float4 w1 = *(const float4*)(Wp + 4);
                wv[0] = w0.x; wv[1] = w0.y; wv[2] = w0.z; wv[3] = w0.w;
                wv[4] = w1.x; wv[5] = w1.y; wv[6] = w1.z; wv[7] = w1.w;
            }
        }
        #pragma unroll
        for (int j = 0; j < 8; ++j) Ws[lk + j][lrow] = wv[j];
        __syncthreads();

        #pragma unroll
        for (int k = 0; k < 16; ++k) {
            float a[8], b[8];
            *(float4*)&a[0] = *(const float4*)&As[k][ty * 8];
            *(float4*)&a[4] = *(const float4*)&As[k][ty * 8 + 4];
            *(float4*)&b[0] = *(const float4*)&Ws[k][tx * 8];
            *(float4*)&b[4] = *(const float4*)&Ws[k][tx * 8 + 4];
            #pragma unroll
            for (int i = 0; i < 8; ++i)
                #pragma unroll
                for (int j = 0; j < 8; ++j)
                    acc[i][j] = fmaf(a[i], b[j], acc[i][j]);
        }
        __syncthreads();
    }

    #pragma unroll
    for (int i = 0; i < 8; ++i) {
        int m = bm + ty * 8 + i;
        #pragma unroll
        for (int jq = 0; jq < 2; ++jq) {
            int ncol = bn + tx * 8 + jq * 4;
            if (ncol < N) {
                float v[4];
                #pragma unroll
                for (int j = 0; j < 4; ++j) {
                    float t = acc[i][jq * 4 + j];
                    int n = ncol + j;
                    if (EPI == EPI_SP) {
                        t += ldw(bias, n, wbf);
                        t = (t > 20.f) ? t : log1pf(__expf(t));
                    }
                    v[j] = t;
                }
                if (CBF) {
                    ushort4 o;
                    o.x = f2bs(v[0]); o.y = f2bs(v[1]); o.z = f2bs(v[2]); o.w = f2bs(v[3]);
                    *(ushort4*)((unsigned short*)Cout + (size_t)m * ldc + ncol) = o;
                } else {
                    *(float4*)((float*)Cout + (size_t)m * ldc + ncol) = *(float4*)v;
                }
            }
        }
    }
}

// ------------------------------------------------- depthwise conv3 + SiLU
__global__ __launch_bounds__(256) void conv_silu_kernel(
    const unsigned short* __restrict__ xz,
    const void* __restrict__ wx, const void* __restrict__ wz,
    unsigned short* __restrict__ u, unsigned short* __restrict__ z,
    const int* __restrict__ flagp)
{
    const bool wbf = (*flagp != 0);
    int bl = blockIdx.x, t = threadIdx.x;
    int l = bl % L_;
    const unsigned short* r = xz + (size_t)bl * 512;
    bool hasm = (l > 0), hasp = (l < L_ - 1);

    float xm = hasm ? bf2f(r[(int)t - 512]) : 0.f;
    float xc = bf2f(r[t]);
    float xp = hasp ? bf2f(r[t + 512]) : 0.f;
    float v = xm * ldw(wx, 3 * t, wbf) + xc * ldw(wx, 3 * t + 1, wbf) + xp * ldw(wx, 3 * t + 2, wbf);
    v = v / (1.f + __expf(-v));
    u[(size_t)bl * 256 + t] = f2bs(v);

    float zm = hasm ? bf2f(r[(int)t - 256]) : 0.f;
    float zc = bf2f(r[256 + t]);
    float zp = hasp ? bf2f(r[768 + t]) : 0.f;
    float vz = zm * ldw(wz, 3 * t, wbf) + zc * ldw(wz, 3 * t + 1, wbf) + zp * ldw(wz, 3 * t + 2, wbf);
    vz = vz / (1.f + __expf(-vz));
    z[(size_t)bl * 256 + t] = f2bs(vz);
}

// ------------------------------------------------- selective scan (chunked)
__global__ __launch_bounds__(256) void scan_a_kernel(
    const unsigned short* __restrict__ delta, const unsigned short* __restrict__ u,
    const float* __restrict__ xdbl, const void* __restrict__ A_log,
    float* __restrict__ hend, float* __restrict__ dsum, const int* __restrict__ flagp)
{
    const bool wbf = (*flagp != 0);
    int blk = blockIdx.x;
    int b = blk / (NCH * 16);
    int rem = blk % (NCH * 16);
    int c = rem / 16, db = rem % 16;
    int g = threadIdx.x >> 4, n = threadIdx.x & 15;
    int d = db * 16 + g;

    float An = -__expf(ldw(A_log, d * 16 + n, wbf));
    float h = 0.f, s = 0.f;
    const unsigned short* dp = delta + (size_t)b * L_ * 256;
    const unsigned short* up = u     + (size_t)b * L_ * 256;
    const float* xd = xdbl + (size_t)b * L_ * 48;
    int lbase = c * LCH;
    for (int t2 = 0; t2 < LCH; ++t2) {
        int l = lbase + t2;
        float ds = bf2f(dp[(size_t)l * 256 + d]);
        float ut = bf2f(up[(size_t)l * 256 + d]);
        float Bn = xd[(size_t)l * 48 + 16 + n];
        h = __expf(ds * An) * h + ds * Bn * ut;
        s += ds;
    }
    size_t pair = (size_t)b * 256 + d;
    hend[(pair * NCH + c) * 16 + n] = h;
    if (n == 0) dsum[pair * NCH + c] = s;
}

__global__ __launch_bounds__(256) void scan_b_kernel(
    const void* __restrict__ A_log, float* __restrict__ hend,
    const float* __restrict__ dsum, const int* __restrict__ flagp)
{
    const bool wbf = (*flagp != 0);
    int gid = blockIdx.x * 256 + threadIdx.x;   // 16384
    int pair = gid >> 4, n = gid & 15;
    int d = pair & 255;
    float An = -__expf(ldw(A_log, d * 16 + n, wbf));
    float H = 0.f;
    for (int c = 0; c < NCH; ++c) {
        size_t idx = ((size_t)pair * NCH + c) * 16 + n;
        float he = hend[idx];
        hend[idx] = H;
        H = __expf(An * dsum[(size_t)pair * NCH + c]) * H + he;
    }
}

__global__ __launch_bounds__(256) void scan_c_kernel(
    const unsigned short* __restrict__ delta, const unsigned short* __restrict__ u,
    const float* __restrict__ xdbl, const void* __restrict__ A_log,
    const void* __restrict__ Dp, const float* __restrict__ hinit,
    unsigned short* __restrict__ y, const int* __restrict__ flagp)
{
    const bool wbf = (*flagp != 0);
    int blk = blockIdx.x;
    int b = blk / (NCH * 16);
    int rem = blk % (NCH * 16);
    int c = rem / 16, db = rem % 16;
    int g = threadIdx.x >> 4, n = threadIdx.x & 15;
    int d = db * 16 + g;

    float An = -__expf(ldw(A_log, d * 16 + n, wbf));
    float Dd = ldw(Dp, d, wbf);
    size_t pair = (size_t)b * 256 + d;
    float h = hinit[(pair * NCH + c) * 16 + n];
    const unsigned short* dp = delta + (size_t)b * L_ * 256;
    const unsigned short* up = u     + (size_t)b * L_ * 256;
    const float* xd = xdbl + (size_t)b * L_ * 48;
    int lbase = c * LCH;
    for (int t2 = 0; t2 < LCH; ++t2) {
        int l = lbase + t2;
        float ds = bf2f(dp[(size_t)l * 256 + d]);
        float ut = bf2f(up[(size_t)l * 256 + d]);
        float Bn = xd[(size_t)l * 48 + 16 + n];
        float Cn = xd[(size_t)l * 48 + 32 + n];
        h = __expf(ds * An) * h + ds * Bn * ut;
        float yp = h * Cn;
        yp += __shfl_xor(yp, 1);
        yp += __shfl_xor(yp, 2);
        yp += __shfl_xor(yp, 4);
        yp += __shfl_xor(yp, 8);
        if (n == 0)
            y[((size_t)b * L_ + l) * 256 + d] = f2bs(yp + ut * Dd);
    }
}

// ------------------------------------------------- launch
extern "C" void kernel_launch(void* const* d_in, const int* in_sizes, int n_in,
                              void* d_out, int out_size, void* d_ws, size_t ws_size,
                              hipStream_t stream) {
    const void* x         = d_in[0];
    const void* ln1_g     = d_in[1];
    const void* ln1_b     = d_in[2];
    const void* ln2_g     = d_in[3];
    const void* ln2_b     = d_in[4];
    const void* in_proj_w = d_in[5];
    const void* conv_x_w  = d_in[6];
    const void* conv_z_w  = d_in[7];
    const void* x_proj_w  = d_in[8];
    const void* dt_proj_w = d_in[9];
    const void* dt_proj_b = d_in[10];
    const void* A_log     = d_in[11];
    const void* Dp        = d_in[12];
    const void* out_proj_w= d_in[13];
    const void* mlp_w1    = d_in[14];
    const void* mlp_b1    = d_in[15];
    const void* mlp_w2    = d_in[16];
    const void* mlp_b2    = d_in[17];

    float* ws = (float*)d_ws;
    unsigned short* xz    = (unsigned short*)(ws);
    unsigned short* delta = (unsigned short*)(ws);
    unsigned short* yb    = (unsigned short*)(ws + 1605632);
    float*          xdbl  = ws + 3211264;
    float*          hend  = ws + 3813376;
    float*          dsum  = ws + 4616192;
    unsigned short* hmid  = (unsigned short*)(ws);
    unsigned short* ub    = (unsigned short*)(ws + 6422528);
    unsigned short* xres  = (unsigned short*)(ws + 6422528);
    unsigned short* xnb   = (unsigned short*)(ws + 8028160);
    int*            flag  = (int*)(ws + 9633792);

    dim3 blk(256);
    const int KNOSPLIT = 1 << 30;

    // 0. dtype detection -> flag
    detect_kernel<<<1, blk, 0, stream>>>((const unsigned int*)x, flag);

    // 1. LN1: x(dual) -> xn (bf16)
    ln_kernel<<<M_, blk, 0, stream>>>(x, -1, ln1_g, ln1_b, xnb, flag);

    // 2. in_proj (MFMA): xn (M,256) x W(512,256)^T -> xz (M,512) bf16
    mgemm_kernel<EPI_NONE><<<dim3(4, 98), blk, 0, stream>>>(
        xnb, nullptr, KNOSPLIT, in_proj_w, xz, 512, 256, 256, 512, nullptr, nullptr, nullptr, flag);

    // 3. conv+silu: xz -> u (bf16), z (bf16, overwrites xn)
    conv_silu_kernel<<<M_, blk, 0, stream>>>(xz, conv_x_w, conv_z_w, ub, xnb, flag);

    // 4. x_proj: u (M,256) x W(48,256)^T -> xdbl (M,48) fp32
    gemm_kernel<EPI_NONE, true, false><<<dim3(1, 98), blk, 0, stream>>>(
        ub, nullptr, 256, x_proj_w, xdbl, 48, 256, 256, 48, nullptr, nullptr, nullptr, flag);

    // 5. dt_proj + softplus: xdbl[:,:16] x W(256,16)^T -> delta (bf16)
    gemm_kernel<EPI_SP, false, true><<<dim3(2, 98), blk, 0, stream>>>(
        xdbl, nullptr, 16, dt_proj_w, delta, 256, 16, 48, 256, dt_proj_b, nullptr, nullptr, flag);

    // 6-8. selective scan
    scan_a_kernel<<<B_ * NCH * 16, blk, 0, stream>>>(delta, ub, xdbl, A_log, hend, dsum, flag);
    scan_b_kernel<<<64, blk, 0, stream>>>(A_log, hend, dsum, flag);
    scan_c_kernel<<<B_ * NCH * 16, blk, 0, stream>>>(delta, ub, xdbl, A_log, Dp, hend, yb, flag);

    // 9. out_proj + residual (MFMA, split A = [y | z]): -> xres bf16
    mgemm_kernel<EPI_RES><<<dim3(2, 98), blk, 0, stream>>>(
        yb, xnb, 256, out_proj_w, xres, 256, 512, 256, 256, nullptr, x, nullptr, flag);

    // 10. LN2: xres -> xn2 (bf16, overwrites z)
    ln_kernel<<<M_, blk, 0, stream>>>(xres, 1, ln2_g, ln2_b, xnb, flag);

    // 11. MLP1 + bias + GELU (MFMA): xn2 x W(1024,256)^T -> hmid bf16
    mgemm_kernel<EPI_GELU><<<dim3(8, 98), blk, 0, stream>>>(
        xnb, nullptr, KNOSPLIT, mlp_w1, hmid, 1024, 256, 256, 1024, mlp_b1, nullptr, nullptr, flag);

    // 12. MLP2 + bias + residual (MFMA) -> d_out (dtype per flag)
    mgemm_kernel<EPI_OUT><<<dim3(2, 98), blk, 0, stream>>>(
        hmid, nullptr, KNOSPLIT, mlp_w2, d_out, 256, 1024, 1024, 256, mlp_b2, nullptr, xres, flag);
}

// Round 2
// 437.711 us; speedup vs baseline: 1.8032x; 1.0066x over previous
//
#include <hip/hip_runtime.h>
#include <hip/hip_bf16.h>

#define B_ 4
#define L_ 3136
#define D_ 256
#define NCH 49     // 49 chunks * 64 = 3136
#define LCH 64
#define M_ (B_*L_)

__device__ __forceinline__ float bf2f(unsigned short u) {
    union { unsigned int i; float f; } v; v.i = ((unsigned int)u) << 16; return v.f;
}
__device__ __forceinline__ unsigned short f2bs(float f) {
    __hip_bfloat16 h = __float2bfloat16(f);
    return *(unsigned short*)&h;
}
// dual-dtype load for INPUT tensors (bf16 if flag, else fp32)
__device__ __forceinline__ float ldw(const void* p, size_t i, bool bf) {
    return bf ? bf2f(((const unsigned short*)p)[i]) : ((const float*)p)[i];
}
__device__ __forceinline__ void cvt4(ushort4 a, float* o) {
    o[0] = bf2f(a.x); o[1] = bf2f(a.y); o[2] = bf2f(a.z); o[3] = bf2f(a.w);
}

// ------------------------------------------------- dtype detection
__global__ __launch_bounds__(256) void detect_kernel(
    const unsigned int* __restrict__ xw, int* __restrict__ flag)
{
    int t = threadIdx.x; int cnt = 0;
    for (int i = t; i < 2048; i += 256) {
        unsigned int lo = xw[i] & 0xFFFFu;
        unsigned int e = (lo >> 7) & 0xFFu;
        if (e >= 0x58u && e <= 0x97u) cnt++;
    }
    #pragma unroll
    for (int o = 32; o > 0; o >>= 1) cnt += __shfl_down(cnt, o);
    __shared__ int sred[4];
    if ((t & 63) == 0) sred[t >> 6] = cnt;
    __syncthreads();
    if (t == 0) flag[0] = (sred[0] + sred[1] + sred[2] + sred[3] > 1024) ? 1 : 0;
}

// ------------------------------------------------- LayerNorm (1 wave = 1 row, 4 elem/thread)
__global__ __launch_bounds__(256) void ln_kernel(
    const void* __restrict__ xin, int inmode,   // -1: dual via flag; 1: bf16
    const void* __restrict__ g, const void* __restrict__ bsh,
    unsigned short* __restrict__ out, const int* __restrict__ flagp)
{
    const bool wbf = (*flagp != 0);
    const bool inbf = (inmode < 0) ? wbf : true;
    int row = blockIdx.x * 4 + (threadIdx.x >> 6);
    int lane = threadIdx.x & 63;
    size_t idx = (size_t)row * 256 + lane * 4;
    float v[4];
    if (inbf) {
        ushort4 a = *(const ushort4*)((const unsigned short*)xin + idx);
        cvt4(a, v);
    } else {
        float4 a = *(const float4*)((const float*)xin + idx);
        v[0] = a.x; v[1] = a.y; v[2] = a.z; v[3] = a.w;
    }
    float s = v[0] + v[1] + v[2] + v[3];
    float s2 = v[0]*v[0] + v[1]*v[1] + v[2]*v[2] + v[3]*v[3];
    #pragma unroll
    for (int o = 32; o > 0; o >>= 1) { s += __shfl_xor(s, o); s2 += __shfl_xor(s2, o); }
    float mean = s * (1.f / 256.f);
    float var  = s2 * (1.f / 256.f) - mean * mean;
    float rs = rsqrtf(var + 1e-5f);
    ushort4 o;
    o.x = f2bs((v[0] - mean) * rs * ldw(g, lane*4+0, wbf) + ldw(bsh, lane*4+0, wbf));
    o.y = f2bs((v[1] - mean) * rs * ldw(g, lane*4+1, wbf) + ldw(bsh, lane*4+1, wbf));
    o.z = f2bs((v[2] - mean) * rs * ldw(g, lane*4+2, wbf) + ldw(bsh, lane*4+2, wbf));
    o.w = f2bs((v[3] - mean) * rs * ldw(g, lane*4+3, wbf) + ldw(bsh, lane*4+3, wbf));
    *(ushort4*)(out + idx) = o;
}

// ------------------------------------------------- epilogue tags
enum { EPI_NONE = 0, EPI_SP = 1, EPI_RES = 2, EPI_GELU = 3, EPI_OUT = 4 };

// ------------------------------------------------- MFMA bf16 GEMM
typedef __attribute__((ext_vector_type(8))) short bf16x8;
typedef __attribute__((ext_vector_type(4))) float f32x4;

__device__ __forceinline__ void gload_lds16(const void* g, void* l) {
    __builtin_amdgcn_global_load_lds(
        (const __attribute__((address_space(1))) unsigned int*)g,
        (__attribute__((address_space(3))) unsigned int*)l, 16, 0, 0);
}

template<int EPI>
__global__ __launch_bounds__(256) void mgemm_kernel(
    const unsigned short* __restrict__ A, const unsigned short* __restrict__ A2, int Ksplit,
    const void* __restrict__ W, void* __restrict__ Cout,
    int N, int K, int lda, int ldc,
    const void* __restrict__ bias, const void* __restrict__ resb,
    const unsigned short* __restrict__ resf, const int* __restrict__ flagp)
{
    const bool wbf = (*flagp != 0);
    __shared__ unsigned short As[128][32];
    __shared__ unsigned short Ws[128][32];
    const int tid = threadIdx.x;
    const int bm = blockIdx.y * 128, bn = blockIdx.x * 128;
    const int l = tid & 63, wid = tid >> 6;
    const int wr = wid >> 1, wc = wid & 1;
    const int lr = l & 15;
    const int lk = (l >> 4) * 8;
    const int srow = tid >> 2;
    const int scol = (tid & 3) * 8;

    f32x4 acc[4][4] = {};

    for (int k0 = 0; k0 < K; k0 += 32) {
        const unsigned short* Ab; int kc;
        if (k0 < Ksplit) { Ab = A;  kc = k0; }
        else             { Ab = A2; kc = k0 - Ksplit; }
        gload_lds16(Ab + (size_t)(bm + srow) * lda + kc + scol,       &As[srow][scol]);
        gload_lds16(Ab + (size_t)(bm + 64 + srow) * lda + kc + scol,  &As[64 + srow][scol]);
        if (wbf) {
            const unsigned short* Wb = (const unsigned short*)W;
            gload_lds16(Wb + (size_t)(bn + srow) * K + k0 + scol,      &Ws[srow][scol]);
            gload_lds16(Wb + (size_t)(bn + 64 + srow) * K + k0 + scol, &Ws[64 + srow][scol]);
        } else {
            const float* Wf = (const float*)W;
            #pragma unroll
            for (int h = 0; h < 2; ++h) {
                const float* p = Wf + (size_t)(bn + h * 64 + srow) * K + k0 + scol;
                float4 w0 = *(const float4*)p;
                float4 w1 = *(const float4*)(p + 4);
                ushort4 o0, o1;
                o0.x = f2bs(w0.x); o0.y = f2bs(w0.y); o0.z = f2bs(w0.z); o0.w = f2bs(w0.w);
                o1.x = f2bs(w1.x); o1.y = f2bs(w1.y); o1.z = f2bs(w1.z); o1.w = f2bs(w1.w);
                *(ushort4*)&Ws[h * 64 + srow][scol]     = o0;
                *(ushort4*)&Ws[h * 64 + srow][scol + 4] = o1;
            }
        }
        asm volatile("s_waitcnt vmcnt(0)" ::: "memory");
        __syncthreads();

        bf16x8 af[4], bfr[4];
        #pragma unroll
        for (int i = 0; i < 4; ++i) {
            af[i]  = *(const bf16x8*)&As[wr * 64 + i * 16 + lr][lk];
            bfr[i] = *(const bf16x8*)&Ws[wc * 64 + i * 16 + lr][lk];
        }
        #pragma unroll
        for (int i = 0; i < 4; ++i)
            #pragma unroll
            for (int j = 0; j < 4; ++j)
                acc[i][j] = __builtin_amdgcn_mfma_f32_16x16x32_bf16(af[i], bfr[j], acc[i][j], 0, 0, 0);
        __syncthreads();
    }

    #pragma unroll
    for (int i = 0; i < 4; ++i) {
        #pragma unroll
        for (int j = 0; j < 4; ++j) {
            const int col = bn + wc * 64 + j * 16 + lr;
            #pragma unroll
            for (int e = 0; e < 4; ++e) {
                const int row = bm + wr * 64 + i * 16 + (l >> 4) * 4 + e;
                float t = acc[i][j][e];
                if (EPI == EPI_RES) {
                    t += ldw(resb, (size_t)row * 256 + col, wbf);
                } else if (EPI == EPI_GELU) {
                    t += ldw(bias, col, wbf);
                    t = 0.5f * t * (1.f + erff(t * 0.70710678118654752f));
                } else if (EPI == EPI_OUT) {
                    t += ldw(bias, col, wbf) + bf2f(resf[(size_t)row * 256 + col]);
                }
                if (EPI == EPI_OUT && !wbf) {
                    ((float*)Cout)[(size_t)row * ldc + col] = t;
                } else {
                    ((unsigned short*)Cout)[(size_t)row * ldc + col] = f2bs(t);
                }
            }
        }
    }
}

// ------------------------------------------------- small fp32 GEMM (x_proj, dt_proj)
template<int EPI, bool ABF, bool CBF>
__global__ __launch_bounds__(256) void gemm_kernel(
    const void* __restrict__ A, const void* __restrict__ A2, int Ksplit,
    const void* __restrict__ W, void* __restrict__ Cout,
    int N, int K, int lda, int ldc,
    const void* __restrict__ bias, const void* __restrict__ resb,
    const unsigned short* __restrict__ resf, const int* __restrict__ flagp)
{
    const bool wbf = (*flagp != 0);
    __shared__ float As[16][132];
    __shared__ float Ws[16][132];
    const int tid = threadIdx.x;
    const int bm = blockIdx.y * 128, bn = blockIdx.x * 128;
    const int tx = tid & 15, ty = tid >> 4;
    const int lrow = tid >> 1;
    const int lk = (tid & 1) * 8;

    float acc[8][8];
    #pragma unroll
    for (int i = 0; i < 8; ++i)
        #pragma unroll
        for (int j = 0; j < 8; ++j) acc[i][j] = 0.f;

    for (int k0 = 0; k0 < K; k0 += 16) {
        float av[8];
        if (ABF) {
            const unsigned short* Ab; int kc;
            if (k0 < Ksplit) { Ab = (const unsigned short*)A;  kc = k0; }
            else             { Ab = (const unsigned short*)A2; kc = k0 - Ksplit; }
            const unsigned short* Ap = Ab + (size_t)(bm + lrow) * lda + kc + lk;
            ushort4 a0 = *(const ushort4*)Ap;
            ushort4 a1 = *(const ushort4*)(Ap + 4);
            av[0] = bf2f(a0.x); av[1] = bf2f(a0.y); av[2] = bf2f(a0.z); av[3] = bf2f(a0.w);
            av[4] = bf2f(a1.x); av[5] = bf2f(a1.y); av[6] = bf2f(a1.z); av[7] = bf2f(a1.w);
        } else {
            const float* Ap = (const float*)A + (size_t)(bm + lrow) * lda + k0 + lk;
            float4 a0 = *(const float4*)Ap;
            float4 a1 = *(const float4*)(Ap + 4);
            av[0] = a0.x; av[1] = a0.y; av[2] = a0.z; av[3] = a0.w;
            av[4] = a1.x; av[5] = a1.y; av[6] = a1.z; av[7] = a1.w;
        }
        #pragma unroll
        for (int j = 0; j < 8; ++j) As[lk + j][lrow] = av[j];

        int n = bn + lrow;
        float wv[8];
        #pragma unroll
        for (int j = 0; j < 8; ++j) wv[j] = 0.f;
        if (n < N) {
            if (wbf) {
                const unsigned short* Wp = (const unsigned short*)W + (size_t)n * K + k0 + lk;
                ushort4 w0 = *(const ushort4*)Wp;
                ushort4 w1 = *(const ushort4*)(Wp + 4);
                wv[0] = bf2f(w0.x); wv[1] = bf2f(w0.y); wv[2] = bf2f(w0.z); wv[3] = bf2f(w0.w);
                wv[4] = bf2f(w1.x); wv[5] = bf2f(w1.y); wv[6] = bf2f(w1.z); wv[7] = bf2f(w1.w);
            } else {
                const float* Wp = (const float*)W + (size_t)n * K + k0 + lk;
                float4 w0 = *(const float4*)Wp;
                float4 w1 = *(const float4*)(Wp + 4);
                wv[0] = w0.x; wv[1] = w0.y; wv[2] = w0.z; wv[3] = w0.w;
                wv[4] = w1.x; wv[5] = w1.y; wv[6] = w1.z; wv[7] = w1.w;
            }
        }
        #pragma unroll
        for (int j = 0; j < 8; ++j) Ws[lk + j][lrow] = wv[j];
        __syncthreads();

        #pragma unroll
        for (int k = 0; k < 16; ++k) {
            float a[8], b[8];
            *(float4*)&a[0] = *(const float4*)&As[k][ty * 8];
            *(float4*)&a[4] = *(const float4*)&As[k][ty * 8 + 4];
            *(float4*)&b[0] = *(const float4*)&Ws[k][tx * 8];
            *(float4*)&b[4] = *(const float4*)&Ws[k][tx * 8 + 4];
            #pragma unroll
            for (int i = 0; i < 8; ++i)
                #pragma unroll
                for (int j = 0; j < 8; ++j)
                    acc[i][j] = fmaf(a[i], b[j], acc[i][j]);
        }
        __syncthreads();
    }

    #pragma unroll
    for (int i = 0; i < 8; ++i) {
        int m = bm + ty * 8 + i;
        #pragma unroll
        for (int jq = 0; jq < 2; ++jq) {
            int ncol = bn + tx * 8 + jq * 4;
            if (ncol < N) {
                float v[4];
                #pragma unroll
                for (int j = 0; j < 4; ++j) {
                    float t = acc[i][jq * 4 + j];
                    int n = ncol + j;
                    if (EPI == EPI_SP) {
                        t += ldw(bias, n, wbf);
                        t = (t > 20.f) ? t : log1pf(__expf(t));
                    }
                    v[j] = t;
                }
                if (CBF) {
                    ushort4 o;
                    o.x = f2bs(v[0]); o.y = f2bs(v[1]); o.z = f2bs(v[2]); o.w = f2bs(v[3]);
                    *(ushort4*)((unsigned short*)Cout + (size_t)m * ldc + ncol) = o;
                } else {
                    *(float4*)((float*)Cout + (size_t)m * ldc + ncol) = *(float4*)v;
                }
            }
        }
    }
}

// ------------------------------------------------- depthwise conv3 + SiLU (4 rows/block, 4 ch/thread)
__global__ __launch_bounds__(256) void conv_silu_kernel(
    const unsigned short* __restrict__ xz,
    const void* __restrict__ wx, const void* __restrict__ wz,
    unsigned short* __restrict__ u, unsigned short* __restrict__ z,
    const int* __restrict__ flagp)
{
    const bool wbf = (*flagp != 0);
    int sub = threadIdx.x >> 6;
    int c4 = (threadIdx.x & 63) * 4;
    int bl = blockIdx.x * 4 + sub;
    int l = bl % L_;
    const unsigned short* r = xz + (size_t)bl * 512;
    bool hasm = (l > 0), hasp = (l < L_ - 1);
    ushort4 zz; zz.x = 0; zz.y = 0; zz.z = 0; zz.w = 0;

    // x path: channels c4..c4+3
    float xm[4], xc[4], xp[4];
    cvt4(hasm ? *(const ushort4*)(r + c4 - 512) : zz, xm);
    cvt4(*(const ushort4*)(r + c4), xc);
    cvt4(hasp ? *(const ushort4*)(r + c4 + 512) : zz, xp);
    ushort4 uo;
    {
        float o[4];
        #pragma unroll
        for (int j = 0; j < 4; ++j) {
            int cch = c4 + j;
            float v = xm[j] * ldw(wx, 3*cch, wbf) + xc[j] * ldw(wx, 3*cch+1, wbf) + xp[j] * ldw(wx, 3*cch+2, wbf);
            o[j] = v / (1.f + __expf(-v));
        }
        uo.x = f2bs(o[0]); uo.y = f2bs(o[1]); uo.z = f2bs(o[2]); uo.w = f2bs(o[3]);
    }
    *(ushort4*)(u + (size_t)bl * 256 + c4) = uo;

    // z path: channels 256+c4..
    float zm[4], zc[4], zp[4];
    cvt4(hasm ? *(const ushort4*)(r + c4 - 256) : zz, zm);
    cvt4(*(const ushort4*)(r + 256 + c4), zc);
    cvt4(hasp ? *(const ushort4*)(r + 768 + c4) : zz, zp);
    ushort4 zo;
    {
        float o[4];
        #pragma unroll
        for (int j = 0; j < 4; ++j) {
            int cch = c4 + j;
            float v = zm[j] * ldw(wz, 3*cch, wbf) + zc[j] * ldw(wz, 3*cch+1, wbf) + zp[j] * ldw(wz, 3*cch+2, wbf);
            o[j] = v / (1.f + __expf(-v));
        }
        zo.x = f2bs(o[0]); zo.y = f2bs(o[1]); zo.z = f2bs(o[2]); zo.w = f2bs(o[3]);
    }
    *(ushort4*)(z + (size_t)bl * 256 + c4) = zo;
}

// ------------------------------------------------- selective scan (chunked, LDS-staged)
__global__ __launch_bounds__(256) void scan_a_kernel(
    const unsigned short* __restrict__ delta, const unsigned short* __restrict__ u,
    const float* __restrict__ xdbl, const void* __restrict__ A_log,
    float* __restrict__ hend, float* __restrict__ dsum, const int* __restrict__ flagp)
{
    const bool wbf = (*flagp != 0);
    int blk = blockIdx.x;
    int b = blk / (NCH * 16);
    int rem = blk % (NCH * 16);
    int c = rem / 16, db = rem % 16;

    __shared__ unsigned short sd[64][16];
    __shared__ unsigned short su[64][16];
    __shared__ float sB[64][16];

    const unsigned short* dp = delta + (size_t)b * L_ * 256;
    const unsigned short* up = u     + (size_t)b * L_ * 256;
    const float* xd = xdbl + (size_t)b * L_ * 48;

    int r = threadIdx.x >> 2, q = (threadIdx.x & 3) * 4;
    int lrow = c * 64 + r;
    *(ushort4*)&sd[r][q] = *(const ushort4*)(dp + (size_t)lrow * 256 + db * 16 + q);
    *(ushort4*)&su[r][q] = *(const ushort4*)(up + (size_t)lrow * 256 + db * 16 + q);
    *(float4*)&sB[r][q]  = *(const float4*)(xd + (size_t)lrow * 48 + 16 + q);
    __syncthreads();

    int g = threadIdx.x >> 4, n = threadIdx.x & 15;
    int d = db * 16 + g;
    float An = -__expf(ldw(A_log, d * 16 + n, wbf));
    float h = 0.f, s = 0.f;
    #pragma unroll 8
    for (int t2 = 0; t2 < 64; ++t2) {
        float ds = bf2f(sd[t2][g]);
        float ut = bf2f(su[t2][g]);
        float Bn = sB[t2][n];
        h = __expf(ds * An) * h + ds * Bn * ut;
        s += ds;
    }
    size_t pair = (size_t)b * 256 + d;
    hend[(pair * NCH + c) * 16 + n] = h;
    if (n == 0) dsum[pair * NCH + c] = s;
}

__global__ __launch_bounds__(256) void scan_b_kernel(
    const void* __restrict__ A_log, float* __restrict__ hend,
    const float* __restrict__ dsum, const int* __restrict__ flagp)
{
    const bool wbf = (*flagp != 0);
    int gid = blockIdx.x * 256 + threadIdx.x;   // 16384
    int pair = gid >> 4, n = gid & 15;
    int d = pair & 255;
    float An = -__expf(ldw(A_log, d * 16 + n, wbf));
    float H = 0.f;
    #pragma unroll 7
    for (int c = 0; c < NCH; ++c) {
        size_t idx = ((size_t)pair * NCH + c) * 16 + n;
        float he = hend[idx];
        hend[idx] = H;
        H = __expf(An * dsum[(size_t)pair * NCH + c]) * H + he;
    }
}

__global__ __launch_bounds__(256) void scan_c_kernel(
    const unsigned short* __restrict__ delta, const unsigned short* __restrict__ u,
    const float* __restrict__ xdbl, const void* __restrict__ A_log,
    const void* __restrict__ Dp, const float* __restrict__ hinit,
    unsigned short* __restrict__ y, const int* __restrict__ flagp)
{
    const bool wbf = (*flagp != 0);
    int blk = blockIdx.x;
    int b = blk / (NCH * 16);
    int rem = blk % (NCH * 16);
    int c = rem / 16, db = rem % 16;

    __shared__ unsigned short sd[64][16];
    __shared__ unsigned short su[64][16];
    __shared__ float sB[64][16];
    __shared__ float sC[64][16];
    __shared__ unsigned short sy[64][16];

    const unsigned short* dp = delta + (size_t)b * L_ * 256;
    const unsigned short* up = u     + (size_t)b * L_ * 256;
    const float* xd = xdbl + (size_t)b * L_ * 48;

    int r = threadIdx.x >> 2, q = (threadIdx.x & 3) * 4;
    int lrow = c * 64 + r;
    *(ushort4*)&sd[r][q] = *(const ushort4*)(dp + (size_t)lrow * 256 + db * 16 + q);
    *(ushort4*)&su[r][q] = *(const ushort4*)(up + (size_t)lrow * 256 + db * 16 + q);
    *(float4*)&sB[r][q]  = *(const float4*)(xd + (size_t)lrow * 48 + 16 + q);
    *(float4*)&sC[r][q]  = *(const float4*)(xd + (size_t)lrow * 48 + 32 + q);
    __syncthreads();

    int g = threadIdx.x >> 4, n = threadIdx.x & 15;
    int d = db * 16 + g;
    float An = -__expf(ldw(A_log, d * 16 + n, wbf));
    float Dd = ldw(Dp, d, wbf);
    size_t pair = (size_t)b * 256 + d;
    float h = hinit[(pair * NCH + c) * 16 + n];
    #pragma unroll 4
    for (int t2 = 0; t2 < 64; ++t2) {
        float ds = bf2f(sd[t2][g]);
        float ut = bf2f(su[t2][g]);
        float Bn = sB[t2][n];
        float Cn = sC[t2][n];
        h = __expf(ds * An) * h + ds * Bn * ut;
        float yp = h * Cn;
        yp += __shfl_xor(yp, 1);
        yp += __shfl_xor(yp, 2);
        yp += __shfl_xor(yp, 4);
        yp += __shfl_xor(yp, 8);
        if (n == 0) sy[t2][g] = f2bs(yp + ut * Dd);
    }
    __syncthreads();
    *(ushort4*)(y + ((size_t)b * L_ + c * 64 + r) * 256 + db * 16 + q) = *(ushort4*)&sy[r][q];
}

// ------------------------------------------------- launch
extern "C" void kernel_launch(void* const* d_in, const int* in_sizes, int n_in,
                              void* d_out, int out_size, void* d_ws, size_t ws_size,
                              hipStream_t stream) {
    const void* x         = d_in[0];
    const void* ln1_g     = d_in[1];
    const void* ln1_b     = d_in[2];
    const void* ln2_g     = d_in[3];
    const void* ln2_b     = d_in[4];
    const void* in_proj_w = d_in[5];
    const void* conv_x_w  = d_in[6];
    const void* conv_z_w  = d_in[7];
    const void* x_proj_w  = d_in[8];
    const void* dt_proj_w = d_in[9];
    const void* dt_proj_b = d_in[10];
    const void* A_log     = d_in[11];
    const void* Dp        = d_in[12];
    const void* out_proj_w= d_in[13];
    const void* mlp_w1    = d_in[14];
    const void* mlp_b1    = d_in[15];
    const void* mlp_w2    = d_in[16];
    const void* mlp_b2    = d_in[17];

    float* ws = (float*)d_ws;
    unsigned short* xz    = (unsigned short*)(ws);
    unsigned short* delta = (unsigned short*)(ws);
    unsigned short* yb    = (unsigned short*)(ws + 1605632);
    float*          xdbl  = ws + 3211264;
    float*          hend  = ws + 3813376;
    float*          dsum  = ws + 4616192;
    unsigned short* hmid  = (unsigned short*)(ws);
    unsigned short* ub    = (unsigned short*)(ws + 6422528);
    unsigned short* xres  = (unsigned short*)(ws + 6422528);
    unsigned short* xnb   = (unsigned short*)(ws + 8028160);
    int*            flag  = (int*)(ws + 9633792);

    dim3 blk(256);
    const int KNOSPLIT = 1 << 30;

    // 0. dtype detection -> flag
    detect_kernel<<<1, blk, 0, stream>>>((const unsigned int*)x, flag);

    // 1. LN1: x(dual) -> xn (bf16)
    ln_kernel<<<M_ / 4, blk, 0, stream>>>(x, -1, ln1_g, ln1_b, xnb, flag);

    // 2. in_proj (MFMA): xn (M,256) x W(512,256)^T -> xz (M,512) bf16
    mgemm_kernel<EPI_NONE><<<dim3(4, 98), blk, 0, stream>>>(
        xnb, nullptr, KNOSPLIT, in_proj_w, xz, 512, 256, 256, 512, nullptr, nullptr, nullptr, flag);

    // 3. conv+silu: xz -> u (bf16), z (bf16, overwrites xn)
    conv_silu_kernel<<<M_ / 4, blk, 0, stream>>>(xz, conv_x_w, conv_z_w, ub, xnb, flag);

    // 4. x_proj: u (M,256) x W(48,256)^T -> xdbl (M,48) fp32
    gemm_kernel<EPI_NONE, true, false><<<dim3(1, 98), blk, 0, stream>>>(
        ub, nullptr, 256, x_proj_w, xdbl, 48, 256, 256, 48, nullptr, nullptr, nullptr, flag);

    // 5. dt_proj + softplus: xdbl[:,:16] x W(256,16)^T -> delta (bf16)
    gemm_kernel<EPI_SP, false, true><<<dim3(2, 98), blk, 0, stream>>>(
        xdbl, nullptr, 16, dt_proj_w, delta, 256, 16, 48, 256, dt_proj_b, nullptr, nullptr, flag);

    // 6-8. selective scan
    scan_a_kernel<<<B_ * NCH * 16, blk, 0, stream>>>(delta, ub, xdbl, A_log, hend, dsum, flag);
    scan_b_kernel<<<64, blk, 0, stream>>>(A_log, hend, dsum, flag);
    scan_c_kernel<<<B_ * NCH * 16, blk, 0, stream>>>(delta, ub, xdbl, A_log, Dp, hend, yb, flag);

    // 9. out_proj + residual (MFMA, split A = [y | z]): -> xres bf16
    mgemm_kernel<EPI_RES><<<dim3(2, 98), blk, 0, stream>>>(
        yb, xnb, 256, out_proj_w, xres, 256, 512, 256, 256, nullptr, x, nullptr, flag);

    // 10. LN2: xres -> xn2 (bf16, overwrites z)
    ln_kernel<<<M_ / 4, blk, 0, stream>>>(xres, 1, ln2_g, ln2_b, xnb, flag);

    // 11. MLP1 + bias + GELU (MFMA): xn2 x W(1024,256)^T -> hmid bf16
    mgemm_kernel<EPI_GELU><<<dim3(8, 98), blk, 0, stream>>>(
        xnb, nullptr, KNOSPLIT, mlp_w1, hmid, 1024, 256, 256, 1024, mlp_b1, nullptr, nullptr, flag);

    // 12. MLP2 + bias + residual (MFMA) -> d_out (dtype per flag)
    mgemm_kernel<EPI_OUT><<<dim3(2, 98), blk, 0, stream>>>(
        hmid, nullptr, KNOSPLIT, mlp_w2, d_out, 256, 1024, 1024, 256, mlp_b2, nullptr, xres, flag);
}

// Round 3
// 410.493 us; speedup vs baseline: 1.9228x; 1.0663x over previous
//
#include <hip/hip_runtime.h>
#include <hip/hip_bf16.h>

#define B_ 4
#define L_ 3136
#define D_ 256
#define NCH 49     // 49 chunks * 64 = 3136
#define LCH 64
#define M_ (B_*L_)

__device__ __forceinline__ float bf2f(unsigned short u) {
    union { unsigned int i; float f; } v; v.i = ((unsigned int)u) << 16; return v.f;
}
__device__ __forceinline__ unsigned short f2bs(float f) {
    __hip_bfloat16 h = __float2bfloat16(f);
    return *(unsigned short*)&h;
}
// dual-dtype load for INPUT tensors (bf16 if flag, else fp32)
__device__ __forceinline__ float ldw(const void* p, size_t i, bool bf) {
    return bf ? bf2f(((const unsigned short*)p)[i]) : ((const float*)p)[i];
}
__device__ __forceinline__ void cvt4(ushort4 a, float* o) {
    o[0] = bf2f(a.x); o[1] = bf2f(a.y); o[2] = bf2f(a.z); o[3] = bf2f(a.w);
}
// DPP cross-lane adds within quads (xor1 / xor2) -- pure VALU, no LDS pipe
__device__ __forceinline__ float dpp_add_xor1(float x) {
    int m = __builtin_amdgcn_update_dpp(0, __float_as_int(x), 0xB1, 0xF, 0xF, true);
    return x + __int_as_float(m);
}
__device__ __forceinline__ float dpp_add_xor2(float x) {
    int m = __builtin_amdgcn_update_dpp(0, __float_as_int(x), 0x4E, 0xF, 0xF, true);
    return x + __int_as_float(m);
}

// ------------------------------------------------- dtype detection
__global__ __launch_bounds__(256) void detect_kernel(
    const unsigned int* __restrict__ xw, int* __restrict__ flag)
{
    int t = threadIdx.x; int cnt = 0;
    for (int i = t; i < 2048; i += 256) {
        unsigned int lo = xw[i] & 0xFFFFu;
        unsigned int e = (lo >> 7) & 0xFFu;
        if (e >= 0x58u && e <= 0x97u) cnt++;
    }
    #pragma unroll
    for (int o = 32; o > 0; o >>= 1) cnt += __shfl_down(cnt, o);
    __shared__ int sred[4];
    if ((t & 63) == 0) sred[t >> 6] = cnt;
    __syncthreads();
    if (t == 0) flag[0] = (sred[0] + sred[1] + sred[2] + sred[3] > 1024) ? 1 : 0;
}

// ------------------------------------------------- LayerNorm (1 wave = 1 row, 4 elem/thread)
__global__ __launch_bounds__(256) void ln_kernel(
    const void* __restrict__ xin, int inmode,   // -1: dual via flag; 1: bf16
    const void* __restrict__ g, const void* __restrict__ bsh,
    unsigned short* __restrict__ out, const int* __restrict__ flagp)
{
    const bool wbf = (*flagp != 0);
    const bool inbf = (inmode < 0) ? wbf : true;
    int row = blockIdx.x * 4 + (threadIdx.x >> 6);
    int lane = threadIdx.x & 63;
    size_t idx = (size_t)row * 256 + lane * 4;
    float v[4];
    if (inbf) {
        ushort4 a = *(const ushort4*)((const unsigned short*)xin + idx);
        cvt4(a, v);
    } else {
        float4 a = *(const float4*)((const float*)xin + idx);
        v[0] = a.x; v[1] = a.y; v[2] = a.z; v[3] = a.w;
    }
    float s = v[0] + v[1] + v[2] + v[3];
    float s2 = v[0]*v[0] + v[1]*v[1] + v[2]*v[2] + v[3]*v[3];
    #pragma unroll
    for (int o = 32; o > 0; o >>= 1) { s += __shfl_xor(s, o); s2 += __shfl_xor(s2, o); }
    float mean = s * (1.f / 256.f);
    float var  = s2 * (1.f / 256.f) - mean * mean;
    float rs = rsqrtf(var + 1e-5f);
    ushort4 o;
    o.x = f2bs((v[0] - mean) * rs * ldw(g, lane*4+0, wbf) + ldw(bsh, lane*4+0, wbf));
    o.y = f2bs((v[1] - mean) * rs * ldw(g, lane*4+1, wbf) + ldw(bsh, lane*4+1, wbf));
    o.z = f2bs((v[2] - mean) * rs * ldw(g, lane*4+2, wbf) + ldw(bsh, lane*4+2, wbf));
    o.w = f2bs((v[3] - mean) * rs * ldw(g, lane*4+3, wbf) + ldw(bsh, lane*4+3, wbf));
    *(ushort4*)(out + idx) = o;
}

// ------------------------------------------------- epilogue tags
enum { EPI_NONE = 0, EPI_SP = 1, EPI_RES = 2, EPI_GELU = 3, EPI_OUT = 4 };

// ------------------------------------------------- MFMA bf16 GEMM (2-phase dbuf)
typedef __attribute__((ext_vector_type(8))) short bf16x8;
typedef __attribute__((ext_vector_type(4))) float f32x4;

__device__ __forceinline__ void gload_lds16(const void* g, void* l) {
    __builtin_amdgcn_global_load_lds(
        (const __attribute__((address_space(1))) unsigned int*)g,
        (__attribute__((address_space(3))) unsigned int*)l, 16, 0, 0);
}

template<int EPI>
__global__ __launch_bounds__(256) void mgemm_kernel(
    const unsigned short* __restrict__ A, const unsigned short* __restrict__ A2, int Ksplit,
    const void* __restrict__ W, void* __restrict__ Cout,
    int N, int K, int lda, int ldc,
    const void* __restrict__ bias, const void* __restrict__ resb,
    const unsigned short* __restrict__ resf, const int* __restrict__ flagp)
{
    const bool wbf = (*flagp != 0);
    __shared__ unsigned short As[2][128][32];
    __shared__ unsigned short Ws[2][128][32];
    const int tid = threadIdx.x;
    const int bm = blockIdx.y * 128, bn = blockIdx.x * 128;
    const int l = tid & 63, wid = tid >> 6;
    const int wr = wid >> 1, wc = wid & 1;
    const int lr = l & 15;
    const int lk = (l >> 4) * 8;
    const int srow = tid >> 2;
    const int scol = (tid & 3) * 8;

    f32x4 acc[4][4] = {};
    const int NT = K >> 5;

    auto stage = [&](int buf, int k0s) {
        const unsigned short* Ab; int kc;
        if (k0s < Ksplit) { Ab = A;  kc = k0s; }
        else              { Ab = A2; kc = k0s - Ksplit; }
        gload_lds16(Ab + (size_t)(bm + srow) * lda + kc + scol,      &As[buf][srow][scol]);
        gload_lds16(Ab + (size_t)(bm + 64 + srow) * lda + kc + scol, &As[buf][64 + srow][scol]);
        if (wbf) {
            const unsigned short* Wb = (const unsigned short*)W;
            gload_lds16(Wb + (size_t)(bn + srow) * K + k0s + scol,      &Ws[buf][srow][scol]);
            gload_lds16(Wb + (size_t)(bn + 64 + srow) * K + k0s + scol, &Ws[buf][64 + srow][scol]);
        } else {
            const float* Wf = (const float*)W;
            #pragma unroll
            for (int h = 0; h < 2; ++h) {
                const float* p = Wf + (size_t)(bn + h * 64 + srow) * K + k0s + scol;
                float4 w0 = *(const float4*)p;
                float4 w1 = *(const float4*)(p + 4);
                ushort4 o0, o1;
                o0.x = f2bs(w0.x); o0.y = f2bs(w0.y); o0.z = f2bs(w0.z); o0.w = f2bs(w0.w);
                o1.x = f2bs(w1.x); o1.y = f2bs(w1.y); o1.z = f2bs(w1.z); o1.w = f2bs(w1.w);
                *(ushort4*)&Ws[buf][h * 64 + srow][scol]     = o0;
                *(ushort4*)&Ws[buf][h * 64 + srow][scol + 4] = o1;
            }
        }
    };

    stage(0, 0);
    asm volatile("s_waitcnt vmcnt(0)" ::: "memory");
    __syncthreads();

    int cur = 0;
    for (int kt = 0; kt < NT; ++kt) {
        if (kt + 1 < NT) stage(cur ^ 1, (kt + 1) << 5);

        bf16x8 af[4], bfr[4];
        #pragma unroll
        for (int i = 0; i < 4; ++i) {
            af[i]  = *(const bf16x8*)&As[cur][wr * 64 + i * 16 + lr][lk];
            bfr[i] = *(const bf16x8*)&Ws[cur][wc * 64 + i * 16 + lr][lk];
        }
        #pragma unroll
        for (int i = 0; i < 4; ++i)
            #pragma unroll
            for (int j = 0; j < 4; ++j)
                acc[i][j] = __builtin_amdgcn_mfma_f32_16x16x32_bf16(af[i], bfr[j], acc[i][j], 0, 0, 0);

        if (kt + 1 < NT) {
            asm volatile("s_waitcnt vmcnt(0)" ::: "memory");
            __syncthreads();
            cur ^= 1;
        }
    }

    #pragma unroll
    for (int i = 0; i < 4; ++i) {
        #pragma unroll
        for (int j = 0; j < 4; ++j) {
            const int col = bn + wc * 64 + j * 16 + lr;
            #pragma unroll
            for (int e = 0; e < 4; ++e) {
                const int row = bm + wr * 64 + i * 16 + (l >> 4) * 4 + e;
                float t = acc[i][j][e];
                if (EPI == EPI_RES) {
                    t += ldw(resb, (size_t)row * 256 + col, wbf);
                } else if (EPI == EPI_GELU) {
                    t += ldw(bias, col, wbf);
                    t = 0.5f * t * (1.f + erff(t * 0.70710678118654752f));
                } else if (EPI == EPI_OUT) {
                    t += ldw(bias, col, wbf) + bf2f(resf[(size_t)row * 256 + col]);
                }
                if (EPI == EPI_OUT && !wbf) {
                    ((float*)Cout)[(size_t)row * ldc + col] = t;
                } else {
                    ((unsigned short*)Cout)[(size_t)row * ldc + col] = f2bs(t);
                }
            }
        }
    }
}

// ------------------------------------------------- small fp32 GEMM (x_proj, dt_proj)
template<int EPI, bool ABF, bool CBF>
__global__ __launch_bounds__(256) void gemm_kernel(
    const void* __restrict__ A, const void* __restrict__ A2, int Ksplit,
    const void* __restrict__ W, void* __restrict__ Cout,
    int N, int K, int lda, int ldc,
    const void* __restrict__ bias, const void* __restrict__ resb,
    const unsigned short* __restrict__ resf, const int* __restrict__ flagp)
{
    const bool wbf = (*flagp != 0);
    __shared__ float As[16][132];
    __shared__ float Ws[16][132];
    const int tid = threadIdx.x;
    const int bm = blockIdx.y * 128, bn = blockIdx.x * 128;
    const int tx = tid & 15, ty = tid >> 4;
    const int lrow = tid >> 1;
    const int lk = (tid & 1) * 8;

    float acc[8][8];
    #pragma unroll
    for (int i = 0; i < 8; ++i)
        #pragma unroll
        for (int j = 0; j < 8; ++j) acc[i][j] = 0.f;

    for (int k0 = 0; k0 < K; k0 += 16) {
        float av[8];
        if (ABF) {
            const unsigned short* Ab; int kc;
            if (k0 < Ksplit) { Ab = (const unsigned short*)A;  kc = k0; }
            else             { Ab = (const unsigned short*)A2; kc = k0 - Ksplit; }
            const unsigned short* Ap = Ab + (size_t)(bm + lrow) * lda + kc + lk;
            ushort4 a0 = *(const ushort4*)Ap;
            ushort4 a1 = *(const ushort4*)(Ap + 4);
            av[0] = bf2f(a0.x); av[1] = bf2f(a0.y); av[2] = bf2f(a0.z); av[3] = bf2f(a0.w);
            av[4] = bf2f(a1.x); av[5] = bf2f(a1.y); av[6] = bf2f(a1.z); av[7] = bf2f(a1.w);
        } else {
            const float* Ap = (const float*)A + (size_t)(bm + lrow) * lda + k0 + lk;
            float4 a0 = *(const float4*)Ap;
            float4 a1 = *(const float4*)(Ap + 4);
            av[0] = a0.x; av[1] = a0.y; av[2] = a0.z; av[3] = a0.w;
            av[4] = a1.x; av[5] = a1.y; av[6] = a1.z; av[7] = a1.w;
        }
        #pragma unroll
        for (int j = 0; j < 8; ++j) As[lk + j][lrow] = av[j];

        int n = bn + lrow;
        float wv[8];
        #pragma unroll
        for (int j = 0; j < 8; ++j) wv[j] = 0.f;
        if (n < N) {
            if (wbf) {
                const unsigned short* Wp = (const unsigned short*)W + (size_t)n * K + k0 + lk;
                ushort4 w0 = *(const ushort4*)Wp;
                ushort4 w1 = *(const ushort4*)(Wp + 4);
                wv[0] = bf2f(w0.x); wv[1] = bf2f(w0.y); wv[2] = bf2f(w0.z); wv[3] = bf2f(w0.w);
                wv[4] = bf2f(w1.x); wv[5] = bf2f(w1.y); wv[6] = bf2f(w1.z); wv[7] = bf2f(w1.w);
            } else {
                const float* Wp = (const float*)W + (size_t)n * K + k0 + lk;
                float4 w0 = *(const float4*)Wp;
                float4 w1 = *(const float4*)(Wp + 4);
                wv[0] = w0.x; wv[1] = w0.y; wv[2] = w0.z; wv[3] = w0.w;
                wv[4] = w1.x; wv[5] = w1.y; wv[6] = w1.z; wv[7] = w1.w;
            }
        }
        #pragma unroll
        for (int j = 0; j < 8; ++j) Ws[lk + j][lrow] = wv[j];
        __syncthreads();

        #pragma unroll
        for (int k = 0; k < 16; ++k) {
            float a[8], b[8];
            *(float4*)&a[0] = *(const float4*)&As[k][ty * 8];
            *(float4*)&a[4] = *(const float4*)&As[k][ty * 8 + 4];
            *(float4*)&b[0] = *(const float4*)&Ws[k][tx * 8];
            *(float4*)&b[4] = *(const float4*)&Ws[k][tx * 8 + 4];
            #pragma unroll
            for (int i = 0; i < 8; ++i)
                #pragma unroll
                for (int j = 0; j < 8; ++j)
                    acc[i][j] = fmaf(a[i], b[j], acc[i][j]);
        }
        __syncthreads();
    }

    #pragma unroll
    for (int i = 0; i < 8; ++i) {
        int m = bm + ty * 8 + i;
        #pragma unroll
        for (int jq = 0; jq < 2; ++jq) {
            int ncol = bn + tx * 8 + jq * 4;
            if (ncol < N) {
                float v[4];
                #pragma unroll
                for (int j = 0; j < 4; ++j) {
                    float t = acc[i][jq * 4 + j];
                    int n = ncol + j;
                    if (EPI == EPI_SP) {
                        t += ldw(bias, n, wbf);
                        t = (t > 20.f) ? t : log1pf(__expf(t));
                    }
                    v[j] = t;
                }
                if (CBF) {
                    ushort4 o;
                    o.x = f2bs(v[0]); o.y = f2bs(v[1]); o.z = f2bs(v[2]); o.w = f2bs(v[3]);
                    *(ushort4*)((unsigned short*)Cout + (size_t)m * ldc + ncol) = o;
                } else {
                    *(float4*)((float*)Cout + (size_t)m * ldc + ncol) = *(float4*)v;
                }
            }
        }
    }
}

// ------------------------------------------------- depthwise conv3 + SiLU (4 rows/block, 4 ch/thread)
__global__ __launch_bounds__(256) void conv_silu_kernel(
    const unsigned short* __restrict__ xz,
    const void* __restrict__ wx, const void* __restrict__ wz,
    unsigned short* __restrict__ u, unsigned short* __restrict__ z,
    const int* __restrict__ flagp)
{
    const bool wbf = (*flagp != 0);
    int sub = threadIdx.x >> 6;
    int c4 = (threadIdx.x & 63) * 4;
    int bl = blockIdx.x * 4 + sub;
    int l = bl % L_;
    const unsigned short* r = xz + (size_t)bl * 512;
    bool hasm = (l > 0), hasp = (l < L_ - 1);
    ushort4 zz; zz.x = 0; zz.y = 0; zz.z = 0; zz.w = 0;

    float xm[4], xc[4], xp[4];
    cvt4(hasm ? *(const ushort4*)(r + c4 - 512) : zz, xm);
    cvt4(*(const ushort4*)(r + c4), xc);
    cvt4(hasp ? *(const ushort4*)(r + c4 + 512) : zz, xp);
    ushort4 uo;
    {
        float o[4];
        #pragma unroll
        for (int j = 0; j < 4; ++j) {
            int cch = c4 + j;
            float v = xm[j] * ldw(wx, 3*cch, wbf) + xc[j] * ldw(wx, 3*cch+1, wbf) + xp[j] * ldw(wx, 3*cch+2, wbf);
            o[j] = v / (1.f + __expf(-v));
        }
        uo.x = f2bs(o[0]); uo.y = f2bs(o[1]); uo.z = f2bs(o[2]); uo.w = f2bs(o[3]);
    }
    *(ushort4*)(u + (size_t)bl * 256 + c4) = uo;

    float zm[4], zc[4], zp[4];
    cvt4(hasm ? *(const ushort4*)(r + c4 - 256) : zz, zm);
    cvt4(*(const ushort4*)(r + 256 + c4), zc);
    cvt4(hasp ? *(const ushort4*)(r + 768 + c4) : zz, zp);
    ushort4 zo;
    {
        float o[4];
        #pragma unroll
        for (int j = 0; j < 4; ++j) {
            int cch = c4 + j;
            float v = zm[j] * ldw(wz, 3*cch, wbf) + zc[j] * ldw(wz, 3*cch+1, wbf) + zp[j] * ldw(wz, 3*cch+2, wbf);
            o[j] = v / (1.f + __expf(-v));
        }
        zo.x = f2bs(o[0]); zo.y = f2bs(o[1]); zo.z = f2bs(o[2]); zo.w = f2bs(o[3]);
    }
    *(ushort4*)(z + (size_t)bl * 256 + c4) = zo;
}

// ------------------------------------------------- selective scan (chunked, DS-minimized)
__global__ __launch_bounds__(256) void scan_a_kernel(
    const unsigned short* __restrict__ delta, const unsigned short* __restrict__ u,
    const float* __restrict__ xdbl, const void* __restrict__ A_log,
    float* __restrict__ hend, float* __restrict__ dsum, const int* __restrict__ flagp)
{
    const bool wbf = (*flagp != 0);
    int blk = blockIdx.x;
    int b = blk / (NCH * 16);
    int rem = blk % (NCH * 16);
    int c = rem / 16, db = rem % 16;

    __shared__ unsigned int sdu[64][16];  // lo: delta, hi: u
    __shared__ float sB[64][16];

    const unsigned short* dp = delta + (size_t)b * L_ * 256;
    const unsigned short* up = u     + (size_t)b * L_ * 256;
    const float* xd = xdbl + (size_t)b * L_ * 48;

    int r = threadIdx.x >> 2, q = (threadIdx.x & 3) * 4;
    int lrow = c * 64 + r;
    {
        ushort4 dv = *(const ushort4*)(dp + (size_t)lrow * 256 + db * 16 + q);
        ushort4 uv = *(const ushort4*)(up + (size_t)lrow * 256 + db * 16 + q);
        uint4 pk;
        pk.x = (unsigned int)dv.x | ((unsigned int)uv.x << 16);
        pk.y = (unsigned int)dv.y | ((unsigned int)uv.y << 16);
        pk.z = (unsigned int)dv.z | ((unsigned int)uv.z << 16);
        pk.w = (unsigned int)dv.w | ((unsigned int)uv.w << 16);
        *(uint4*)&sdu[r][q] = pk;
        *(float4*)&sB[r][q] = *(const float4*)(xd + (size_t)lrow * 48 + 16 + q);
    }
    __syncthreads();

    int g = threadIdx.x >> 4, n = threadIdx.x & 15;
    int d = db * 16 + g;
    float An2 = -__expf(ldw(A_log, d * 16 + n, wbf)) * 1.44269504088896f;
    float h = 0.f, s = 0.f;
    #pragma unroll 8
    for (int t2 = 0; t2 < 64; ++t2) {
        unsigned int du = sdu[t2][g];
        float ds = __uint_as_float(du << 16);
        float ut = __uint_as_float(du & 0xFFFF0000u);
        float Bn = sB[t2][n];
        float e = exp2f(ds * An2);
        h = fmaf(e, h, ds * ut * Bn);
        s += ds;
    }
    size_t pair = (size_t)b * 256 + d;
    hend[(pair * NCH + c) * 16 + n] = h;
    if (n == 0) dsum[pair * NCH + c] = s;
}

__global__ __launch_bounds__(256) void scan_b_kernel(
    const void* __restrict__ A_log, float* __restrict__ hend,
    const float* __restrict__ dsum, const int* __restrict__ flagp)
{
    const bool wbf = (*flagp != 0);
    int gid = blockIdx.x * 256 + threadIdx.x;   // 16384
    int pair = gid >> 4, n = gid & 15;
    int d = pair & 255;
    float An = -__expf(ldw(A_log, d * 16 + n, wbf));
    float H = 0.f;
    #pragma unroll 7
    for (int c = 0; c < NCH; ++c) {
        size_t idx = ((size_t)pair * NCH + c) * 16 + n;
        float he = hend[idx];
        hend[idx] = H;
        H = __expf(An * dsum[(size_t)pair * NCH + c]) * H + he;
    }
}

__global__ __launch_bounds__(256) void scan_c_kernel(
    const unsigned short* __restrict__ delta, const unsigned short* __restrict__ u,
    const float* __restrict__ xdbl, const void* __restrict__ A_log,
    const void* __restrict__ Dp, const float* __restrict__ hinit,
    unsigned short* __restrict__ y, const int* __restrict__ flagp)
{
    const bool wbf = (*flagp != 0);
    int blk = blockIdx.x;
    int b = blk / (NCH * 16);
    int rem = blk % (NCH * 16);
    int c = rem / 16, db = rem % 16;

    __shared__ unsigned int sdu[64][16];     // lo: delta, hi: u  (4 KB)
    __shared__ float sBC[64][16][2];         // [t2][n][B,C]      (8 KB)
    __shared__ float syp[64][16][4];         // quad partials     (16 KB)
    __shared__ unsigned short sy[64][16];    // final bf16 y      (2 KB)

    const unsigned short* dp = delta + (size_t)b * L_ * 256;
    const unsigned short* up = u     + (size_t)b * L_ * 256;
    const float* xd = xdbl + (size_t)b * L_ * 48;

    int r = threadIdx.x >> 2, q = (threadIdx.x & 3) * 4;
    int lrow = c * 64 + r;
    {
        ushort4 dv = *(const ushort4*)(dp + (size_t)lrow * 256 + db * 16 + q);
        ushort4 uv = *(const ushort4*)(up + (size_t)lrow * 256 + db * 16 + q);
        uint4 pk;
        pk.x = (unsigned int)dv.x | ((unsigned int)uv.x << 16);
        pk.y = (unsigned int)dv.y | ((unsigned int)uv.y << 16);
        pk.z = (unsigned int)dv.z | ((unsigned int)uv.z << 16);
        pk.w = (unsigned int)dv.w | ((unsigned int)uv.w << 16);
        *(uint4*)&sdu[r][q] = pk;
        float4 Bv = *(const float4*)(xd + (size_t)lrow * 48 + 16 + q);
        float4 Cv = *(const float4*)(xd + (size_t)lrow * 48 + 32 + q);
        float2 p0; p0.x = Bv.x; p0.y = Cv.x; *(float2*)&sBC[r][q + 0][0] = p0;
        float2 p1; p1.x = Bv.y; p1.y = Cv.y; *(float2*)&sBC[r][q + 1][0] = p1;
        float2 p2; p2.x = Bv.z; p2.y = Cv.z; *(float2*)&sBC[r][q + 2][0] = p2;
        float2 p3; p3.x = Bv.w; p3.y = Cv.w; *(float2*)&sBC[r][q + 3][0] = p3;
    }
    __syncthreads();

    int g = threadIdx.x >> 4, n = threadIdx.x & 15;
    int d = db * 16 + g;
    float An2 = -__expf(ldw(A_log, d * 16 + n, wbf)) * 1.44269504088896f;
    size_t pair = (size_t)b * 256 + d;
    float h = hinit[(pair * NCH + c) * 16 + n];
    const bool wlane = ((n & 3) == 0);
    #pragma unroll 4
    for (int t2 = 0; t2 < 64; ++t2) {
        unsigned int du = sdu[t2][g];
        float ds = __uint_as_float(du << 16);
        float ut = __uint_as_float(du & 0xFFFF0000u);
        float2 bc = *(const float2*)&sBC[t2][n][0];
        float e = exp2f(ds * An2);
        h = fmaf(e, h, ds * ut * bc.x);
        float yp = h * bc.y;
        yp = dpp_add_xor1(yp);
        yp = dpp_add_xor2(yp);
        if (wlane) syp[t2][g][n >> 2] = yp;
    }
    __syncthreads();

    // phase 2: reduce 4 quad-partials per (t2,g), add u*D, convert
    #pragma unroll
    for (int cc = 0; cc < 4; ++cc) {
        int cell = threadIdx.x + cc * 256;
        int t2 = cell >> 4, gg = cell & 15;
        float4 p = *(const float4*)&syp[t2][gg][0];
        unsigned int du = sdu[t2][gg];
        float ut = __uint_as_float(du & 0xFFFF0000u);
        float Dd = ldw(Dp, db * 16 + gg, wbf);
        sy[t2][gg] = f2bs(p.x + p.y + p.z + p.w + ut * Dd);
    }
    __syncthreads();
    *(ushort4*)(y + ((size_t)b * L_ + c * 64 + r) * 256 + db * 16 + q) = *(ushort4*)&sy[r][q];
}

// ------------------------------------------------- launch
extern "C" void kernel_launch(void* const* d_in, const int* in_sizes, int n_in,
                              void* d_out, int out_size, void* d_ws, size_t ws_size,
                              hipStream_t stream) {
    const void* x         = d_in[0];
    const void* ln1_g     = d_in[1];
    const void* ln1_b     = d_in[2];
    const void* ln2_g     = d_in[3];
    const void* ln2_b     = d_in[4];
    const void* in_proj_w = d_in[5];
    const void* conv_x_w  = d_in[6];
    const void* conv_z_w  = d_in[7];
    const void* x_proj_w  = d_in[8];
    const void* dt_proj_w = d_in[9];
    const void* dt_proj_b = d_in[10];
    const void* A_log     = d_in[11];
    const void* Dp        = d_in[12];
    const void* out_proj_w= d_in[13];
    const void* mlp_w1    = d_in[14];
    const void* mlp_b1    = d_in[15];
    const void* mlp_w2    = d_in[16];
    const void* mlp_b2    = d_in[17];

    float* ws = (float*)d_ws;
    unsigned short* xz    = (unsigned short*)(ws);
    unsigned short* delta = (unsigned short*)(ws);
    unsigned short* yb    = (unsigned short*)(ws + 1605632);
    float*          xdbl  = ws + 3211264;
    float*          hend  = ws + 3813376;
    float*          dsum  = ws + 4616192;
    unsigned short* hmid  = (unsigned short*)(ws);
    unsigned short* ub    = (unsigned short*)(ws + 6422528);
    unsigned short* xres  = (unsigned short*)(ws + 6422528);
    unsigned short* xnb   = (unsigned short*)(ws + 8028160);
    int*            flag  = (int*)(ws + 9633792);

    dim3 blk(256);
    const int KNOSPLIT = 1 << 30;

    // 0. dtype detection -> flag
    detect_kernel<<<1, blk, 0, stream>>>((const unsigned int*)x, flag);

    // 1. LN1: x(dual) -> xn (bf16)
    ln_kernel<<<M_ / 4, blk, 0, stream>>>(x, -1, ln1_g, ln1_b, xnb, flag);

    // 2. in_proj (MFMA): xn (M,256) x W(512,256)^T -> xz (M,512) bf16
    mgemm_kernel<EPI_NONE><<<dim3(4, 98), blk, 0, stream>>>(
        xnb, nullptr, KNOSPLIT, in_proj_w, xz, 512, 256, 256, 512, nullptr, nullptr, nullptr, flag);

    // 3. conv+silu: xz -> u (bf16), z (bf16, overwrites xn)
    conv_silu_kernel<<<M_ / 4, blk, 0, stream>>>(xz, conv_x_w, conv_z_w, ub, xnb, flag);

    // 4. x_proj: u (M,256) x W(48,256)^T -> xdbl (M,48) fp32
    gemm_kernel<EPI_NONE, true, false><<<dim3(1, 98), blk, 0, stream>>>(
        ub, nullptr, 256, x_proj_w, xdbl, 48, 256, 256, 48, nullptr, nullptr, nullptr, flag);

    // 5. dt_proj + softplus: xdbl[:,:16] x W(256,16)^T -> delta (bf16)
    gemm_kernel<EPI_SP, false, true><<<dim3(2, 98), blk, 0, stream>>>(
        xdbl, nullptr, 16, dt_proj_w, delta, 256, 16, 48, 256, dt_proj_b, nullptr, nullptr, flag);

    // 6-8. selective scan
    scan_a_kernel<<<B_ * NCH * 16, blk, 0, stream>>>(delta, ub, xdbl, A_log, hend, dsum, flag);
    scan_b_kernel<<<64, blk, 0, stream>>>(A_log, hend, dsum, flag);
    scan_c_kernel<<<B_ * NCH * 16, blk, 0, stream>>>(delta, ub, xdbl, A_log, Dp, hend, yb, flag);

    // 9. out_proj + residual (MFMA, split A = [y | z]): -> xres bf16
    mgemm_kernel<EPI_RES><<<dim3(2, 98), blk, 0, stream>>>(
        yb, xnb, 256, out_proj_w, xres, 256, 512, 256, 256, nullptr, x, nullptr, flag);

    // 10. LN2: xres -> xn2 (bf16, overwrites z)
    ln_kernel<<<M_ / 4, blk, 0, stream>>>(xres, 1, ln2_g, ln2_b, xnb, flag);

    // 11. MLP1 + bias + GELU (MFMA): xn2 x W(1024,256)^T -> hmid bf16
    mgemm_kernel<EPI_GELU><<<dim3(8, 98), blk, 0, stream>>>(
        xnb, nullptr, KNOSPLIT, mlp_w1, hmid, 1024, 256, 256, 1024, mlp_b1, nullptr, nullptr, flag);

    // 12. MLP2 + bias + residual (MFMA) -> d_out (dtype per flag)
    mgemm_kernel<EPI_OUT><<<dim3(2, 98), blk, 0, stream>>>(
        hmid, nullptr, KNOSPLIT, mlp_w2, d_out, 256, 1024, 1024, 256, mlp_b2, nullptr, xres, flag);
}

// Round 4
// 353.365 us; speedup vs baseline: 2.2336x; 1.1617x over previous
//
#include <hip/hip_runtime.h>
#include <hip/hip_bf16.h>

#define B_ 4
#define L_ 3136
#define D_ 256
#define NCH 49     // 49 chunks * 64 = 3136
#define LCH 64
#define M_ (B_*L_)

__device__ __forceinline__ float bf2f(unsigned short u) {
    union { unsigned int i; float f; } v; v.i = ((unsigned int)u) << 16; return v.f;
}
__device__ __forceinline__ unsigned short f2bs(float f) {
    __hip_bfloat16 h = __float2bfloat16(f);
    return *(unsigned short*)&h;
}
// dual-dtype load for INPUT tensors (bf16 if flag, else fp32)
__device__ __forceinline__ float ldw(const void* p, size_t i, bool bf) {
    return bf ? bf2f(((const unsigned short*)p)[i]) : ((const float*)p)[i];
}
__device__ __forceinline__ void cvt4(ushort4 a, float* o) {
    o[0] = bf2f(a.x); o[1] = bf2f(a.y); o[2] = bf2f(a.z); o[3] = bf2f(a.w);
}
// DPP cross-lane adds within quads (xor1 / xor2) -- pure VALU, no LDS pipe
__device__ __forceinline__ float dpp_add_xor1(float x) {
    int m = __builtin_amdgcn_update_dpp(0, __float_as_int(x), 0xB1, 0xF, 0xF, true);
    return x + __int_as_float(m);
}
__device__ __forceinline__ float dpp_add_xor2(float x) {
    int m = __builtin_amdgcn_update_dpp(0, __float_as_int(x), 0x4E, 0xF, 0xF, true);
    return x + __int_as_float(m);
}

// ------------------------------------------------- dtype detection
__global__ __launch_bounds__(256) void detect_kernel(
    const unsigned int* __restrict__ xw, int* __restrict__ flag)
{
    int t = threadIdx.x; int cnt = 0;
    for (int i = t; i < 2048; i += 256) {
        unsigned int lo = xw[i] & 0xFFFFu;
        unsigned int e = (lo >> 7) & 0xFFu;
        if (e >= 0x58u && e <= 0x97u) cnt++;
    }
    #pragma unroll
    for (int o = 32; o > 0; o >>= 1) cnt += __shfl_down(cnt, o);
    __shared__ int sred[4];
    if ((t & 63) == 0) sred[t >> 6] = cnt;
    __syncthreads();
    if (t == 0) flag[0] = (sred[0] + sred[1] + sred[2] + sred[3] > 1024) ? 1 : 0;
}

// ------------------------------------------------- LayerNorm (1 wave = 1 row, 4 elem/thread)
__global__ __launch_bounds__(256) void ln_kernel(
    const void* __restrict__ xin, int inmode,   // -1: dual via flag; 1: bf16
    const void* __restrict__ g, const void* __restrict__ bsh,
    unsigned short* __restrict__ out, const int* __restrict__ flagp)
{
    const bool wbf = (*flagp != 0);
    const bool inbf = (inmode < 0) ? wbf : true;
    int row = blockIdx.x * 4 + (threadIdx.x >> 6);
    int lane = threadIdx.x & 63;
    size_t idx = (size_t)row * 256 + lane * 4;
    float v[4];
    if (inbf) {
        ushort4 a = *(const ushort4*)((const unsigned short*)xin + idx);
        cvt4(a, v);
    } else {
        float4 a = *(const float4*)((const float*)xin + idx);
        v[0] = a.x; v[1] = a.y; v[2] = a.z; v[3] = a.w;
    }
    float s = v[0] + v[1] + v[2] + v[3];
    float s2 = v[0]*v[0] + v[1]*v[1] + v[2]*v[2] + v[3]*v[3];
    #pragma unroll
    for (int o = 32; o > 0; o >>= 1) { s += __shfl_xor(s, o); s2 += __shfl_xor(s2, o); }
    float mean = s * (1.f / 256.f);
    float var  = s2 * (1.f / 256.f) - mean * mean;
    float rs = rsqrtf(var + 1e-5f);
    ushort4 o;
    o.x = f2bs((v[0] - mean) * rs * ldw(g, lane*4+0, wbf) + ldw(bsh, lane*4+0, wbf));
    o.y = f2bs((v[1] - mean) * rs * ldw(g, lane*4+1, wbf) + ldw(bsh, lane*4+1, wbf));
    o.z = f2bs((v[2] - mean) * rs * ldw(g, lane*4+2, wbf) + ldw(bsh, lane*4+2, wbf));
    o.w = f2bs((v[3] - mean) * rs * ldw(g, lane*4+3, wbf) + ldw(bsh, lane*4+3, wbf));
    *(ushort4*)(out + idx) = o;
}

// ------------------------------------------------- epilogue tags
enum { EPI_NONE = 0, EPI_SP = 1, EPI_RES = 2, EPI_GELU = 3, EPI_OUT = 4 };

// ------------------------------------------------- MFMA bf16 GEMM (64x64x64, dbuf, XOR-swizzle)
typedef __attribute__((ext_vector_type(8))) short bf16x8;
typedef __attribute__((ext_vector_type(4))) float f32x4;

__device__ __forceinline__ void gload_lds16(const void* g, void* l) {
    __builtin_amdgcn_global_load_lds(
        (const __attribute__((address_space(1))) unsigned int*)g,
        (__attribute__((address_space(3))) unsigned int*)l, 16, 0, 0);
}

template<int EPI>
__global__ __launch_bounds__(256) void mgemm_kernel(
    const unsigned short* __restrict__ A, const unsigned short* __restrict__ A2, int Ksplit,
    const void* __restrict__ W, void* __restrict__ Cout,
    int N, int K, int lda, int ldc,
    const void* __restrict__ bias, const void* __restrict__ resb,
    const unsigned short* __restrict__ resf, const int* __restrict__ flagp)
{
    const bool wbf = (*flagp != 0);
    __shared__ unsigned short As[2][64][64];
    __shared__ unsigned short Ws[2][64][64];
    const int tid = threadIdx.x;

    // XCD-chunked block swizzle (all grids are %8 == 0)
    const int nwg = gridDim.x * gridDim.y;
    int bid = blockIdx.y * gridDim.x + blockIdx.x;
    int wgid = ((nwg & 7) == 0) ? ((bid & 7) * (nwg >> 3) + (bid >> 3)) : bid;
    const int bx = wgid % gridDim.x;
    const int by = wgid / gridDim.x;
    const int bm = by * 64, bn = bx * 64;

    const int l = tid & 63, wid = tid >> 6;
    const int wr = wid >> 1, wc = wid & 1;   // wave 32x32 quadrant
    const int lr = l & 15;                   // frag row/col
    const int lq = l >> 4;                   // 0..3: k-subgroup / C row group
    const int srow = tid >> 3;               // staging row 0..31
    const int sblk = ((tid & 7) ^ (srow & 7)) * 8;  // swizzled SOURCE elem offset
    const int dcol = (tid & 7) * 8;          // linear LDS dest elem offset

    f32x4 acc[2][2] = {};
    const int NT = K >> 6;

    auto stage = [&](int buf, int k0s) {
        const unsigned short* Ab; int kc;
        if (k0s < Ksplit) { Ab = A;  kc = k0s; }
        else              { Ab = A2; kc = k0s - Ksplit; }
        gload_lds16(Ab + (size_t)(bm + srow) * lda + kc + sblk,      &As[buf][srow][dcol]);
        gload_lds16(Ab + (size_t)(bm + 32 + srow) * lda + kc + sblk, &As[buf][32 + srow][dcol]);
        if (wbf) {
            const unsigned short* Wb = (const unsigned short*)W;
            gload_lds16(Wb + (size_t)(bn + srow) * K + k0s + sblk,      &Ws[buf][srow][dcol]);
            gload_lds16(Wb + (size_t)(bn + 32 + srow) * K + k0s + sblk, &Ws[buf][32 + srow][dcol]);
        } else {
            const float* Wf = (const float*)W;
            #pragma unroll
            for (int h = 0; h < 2; ++h) {
                int row = h * 32 + srow;
                const float* p = Wf + (size_t)(bn + row) * K + k0s + (tid & 7) * 8;
                float4 w0 = *(const float4*)p;
                float4 w1 = *(const float4*)(p + 4);
                ushort4 o0, o1;
                o0.x = f2bs(w0.x); o0.y = f2bs(w0.y); o0.z = f2bs(w0.z); o0.w = f2bs(w0.w);
                o1.x = f2bs(w1.x); o1.y = f2bs(w1.y); o1.z = f2bs(w1.z); o1.w = f2bs(w1.w);
                *(ushort4*)&Ws[buf][row][sblk]     = o0;
                *(ushort4*)&Ws[buf][row][sblk + 4] = o1;
            }
        }
    };

    stage(0, 0);
    asm volatile("s_waitcnt vmcnt(0)" ::: "memory");
    __syncthreads();

    int cur = 0;
    for (int kt = 0; kt < NT; ++kt) {
        if (kt + 1 < NT) stage(cur ^ 1, (kt + 1) << 6);

        bf16x8 af[2][2], bfr[2][2];
        #pragma unroll
        for (int i = 0; i < 2; ++i) {
            #pragma unroll
            for (int ks = 0; ks < 2; ++ks) {
                int ca = ((ks * 4 + lq) ^ (lr & 7)) * 8;   // swizzled read
                af[i][ks]  = *(const bf16x8*)&As[cur][wr * 32 + i * 16 + lr][ca];
                bfr[i][ks] = *(const bf16x8*)&Ws[cur][wc * 32 + i * 16 + lr][ca];
            }
        }
        #pragma unroll
        for (int ks = 0; ks < 2; ++ks)
            #pragma unroll
            for (int i = 0; i < 2; ++i)
                #pragma unroll
                for (int j = 0; j < 2; ++j)
                    acc[i][j] = __builtin_amdgcn_mfma_f32_16x16x32_bf16(af[i][ks], bfr[j][ks], acc[i][j], 0, 0, 0);

        if (kt + 1 < NT) {
            asm volatile("s_waitcnt vmcnt(0)" ::: "memory");
            __syncthreads();
            cur ^= 1;
        }
    }

    // epilogue: C frag: col = lr, row = lq*4 + e
    #pragma unroll
    for (int i = 0; i < 2; ++i) {
        #pragma unroll
        for (int j = 0; j < 2; ++j) {
            const int col = bn + wc * 32 + j * 16 + lr;
            #pragma unroll
            for (int e = 0; e < 4; ++e) {
                const int row = bm + wr * 32 + i * 16 + lq * 4 + e;
                float t = acc[i][j][e];
                if (EPI == EPI_RES) {
                    t += ldw(resb, (size_t)row * 256 + col, wbf);
                } else if (EPI == EPI_GELU) {
                    t += ldw(bias, col, wbf);
                    t = 0.5f * t * (1.f + erff(t * 0.70710678118654752f));
                } else if (EPI == EPI_OUT) {
                    t += ldw(bias, col, wbf) + bf2f(resf[(size_t)row * 256 + col]);
                }
                if (EPI == EPI_OUT && !wbf) {
                    ((float*)Cout)[(size_t)row * ldc + col] = t;
                } else {
                    ((unsigned short*)Cout)[(size_t)row * ldc + col] = f2bs(t);
                }
            }
        }
    }
}

// ------------------------------------------------- small fp32 GEMM (x_proj, dt_proj)
template<int EPI, bool ABF, bool CBF>
__global__ __launch_bounds__(256) void gemm_kernel(
    const void* __restrict__ A, const void* __restrict__ A2, int Ksplit,
    const void* __restrict__ W, void* __restrict__ Cout,
    int N, int K, int lda, int ldc,
    const void* __restrict__ bias, const void* __restrict__ resb,
    const unsigned short* __restrict__ resf, const int* __restrict__ flagp)
{
    const bool wbf = (*flagp != 0);
    __shared__ float As[16][132];
    __shared__ float Ws[16][132];
    const int tid = threadIdx.x;
    const int bm = blockIdx.y * 128, bn = blockIdx.x * 128;
    const int tx = tid & 15, ty = tid >> 4;
    const int lrow = tid >> 1;
    const int lk = (tid & 1) * 8;

    float acc[8][8];
    #pragma unroll
    for (int i = 0; i < 8; ++i)
        #pragma unroll
        for (int j = 0; j < 8; ++j) acc[i][j] = 0.f;

    for (int k0 = 0; k0 < K; k0 += 16) {
        float av[8];
        if (ABF) {
            const unsigned short* Ab; int kc;
            if (k0 < Ksplit) { Ab = (const unsigned short*)A;  kc = k0; }
            else             { Ab = (const unsigned short*)A2; kc = k0 - Ksplit; }
            const unsigned short* Ap = Ab + (size_t)(bm + lrow) * lda + kc + lk;
            ushort4 a0 = *(const ushort4*)Ap;
            ushort4 a1 = *(const ushort4*)(Ap + 4);
            av[0] = bf2f(a0.x); av[1] = bf2f(a0.y); av[2] = bf2f(a0.z); av[3] = bf2f(a0.w);
            av[4] = bf2f(a1.x); av[5] = bf2f(a1.y); av[6] = bf2f(a1.z); av[7] = bf2f(a1.w);
        } else {
            const float* Ap = (const float*)A + (size_t)(bm + lrow) * lda + k0 + lk;
            float4 a0 = *(const float4*)Ap;
            float4 a1 = *(const float4*)(Ap + 4);
            av[0] = a0.x; av[1] = a0.y; av[2] = a0.z; av[3] = a0.w;
            av[4] = a1.x; av[5] = a1.y; av[6] = a1.z; av[7] = a1.w;
        }
        #pragma unroll
        for (int j = 0; j < 8; ++j) As[lk + j][lrow] = av[j];

        int n = bn + lrow;
        float wv[8];
        #pragma unroll
        for (int j = 0; j < 8; ++j) wv[j] = 0.f;
        if (n < N) {
            if (wbf) {
                const unsigned short* Wp = (const unsigned short*)W + (size_t)n * K + k0 + lk;
                ushort4 w0 = *(const ushort4*)Wp;
                ushort4 w1 = *(const ushort4*)(Wp + 4);
                wv[0] = bf2f(w0.x); wv[1] = bf2f(w0.y); wv[2] = bf2f(w0.z); wv[3] = bf2f(w0.w);
                wv[4] = bf2f(w1.x); wv[5] = bf2f(w1.y); wv[6] = bf2f(w1.z); wv[7] = bf2f(w1.w);
            } else {
                const float* Wp = (const float*)W + (size_t)n * K + k0 + lk;
                float4 w0 = *(const float4*)Wp;
                float4 w1 = *(const float4*)(Wp + 4);
                wv[0] = w0.x; wv[1] = w0.y; wv[2] = w0.z; wv[3] = w0.w;
                wv[4] = w1.x; wv[5] = w1.y; wv[6] = w1.z; wv[7] = w1.w;
            }
        }
        #pragma unroll
        for (int j = 0; j < 8; ++j) Ws[lk + j][lrow] = wv[j];
        __syncthreads();

        #pragma unroll
        for (int k = 0; k < 16; ++k) {
            float a[8], b[8];
            *(float4*)&a[0] = *(const float4*)&As[k][ty * 8];
            *(float4*)&a[4] = *(const float4*)&As[k][ty * 8 + 4];
            *(float4*)&b[0] = *(const float4*)&Ws[k][tx * 8];
            *(float4*)&b[4] = *(const float4*)&Ws[k][tx * 8 + 4];
            #pragma unroll
            for (int i = 0; i < 8; ++i)
                #pragma unroll
                for (int j = 0; j < 8; ++j)
                    acc[i][j] = fmaf(a[i], b[j], acc[i][j]);
        }
        __syncthreads();
    }

    #pragma unroll
    for (int i = 0; i < 8; ++i) {
        int m = bm + ty * 8 + i;
        #pragma unroll
        for (int jq = 0; jq < 2; ++jq) {
            int ncol = bn + tx * 8 + jq * 4;
            if (ncol < N) {
                float v[4];
                #pragma unroll
                for (int j = 0; j < 4; ++j) {
                    float t = acc[i][jq * 4 + j];
                    int n = ncol + j;
                    if (EPI == EPI_SP) {
                        t += ldw(bias, n, wbf);
                        t = (t > 20.f) ? t : log1pf(__expf(t));
                    }
                    v[j] = t;
                }
                if (CBF) {
                    ushort4 o;
                    o.x = f2bs(v[0]); o.y = f2bs(v[1]); o.z = f2bs(v[2]); o.w = f2bs(v[3]);
                    *(ushort4*)((unsigned short*)Cout + (size_t)m * ldc + ncol) = o;
                } else {
                    *(float4*)((float*)Cout + (size_t)m * ldc + ncol) = *(float4*)v;
                }
            }
        }
    }
}

// ------------------------------------------------- depthwise conv3 + SiLU (4 rows/block, 4 ch/thread)
__global__ __launch_bounds__(256) void conv_silu_kernel(
    const unsigned short* __restrict__ xz,
    const void* __restrict__ wx, const void* __restrict__ wz,
    unsigned short* __restrict__ u, unsigned short* __restrict__ z,
    const int* __restrict__ flagp)
{
    const bool wbf = (*flagp != 0);
    int sub = threadIdx.x >> 6;
    int c4 = (threadIdx.x & 63) * 4;
    int bl = blockIdx.x * 4 + sub;
    int l = bl % L_;
    const unsigned short* r = xz + (size_t)bl * 512;
    bool hasm = (l > 0), hasp = (l < L_ - 1);
    ushort4 zz; zz.x = 0; zz.y = 0; zz.z = 0; zz.w = 0;

    float xm[4], xc[4], xp[4];
    cvt4(hasm ? *(const ushort4*)(r + c4 - 512) : zz, xm);
    cvt4(*(const ushort4*)(r + c4), xc);
    cvt4(hasp ? *(const ushort4*)(r + c4 + 512) : zz, xp);
    ushort4 uo;
    {
        float o[4];
        #pragma unroll
        for (int j = 0; j < 4; ++j) {
            int cch = c4 + j;
            float v = xm[j] * ldw(wx, 3*cch, wbf) + xc[j] * ldw(wx, 3*cch+1, wbf) + xp[j] * ldw(wx, 3*cch+2, wbf);
            o[j] = v / (1.f + __expf(-v));
        }
        uo.x = f2bs(o[0]); uo.y = f2bs(o[1]); uo.z = f2bs(o[2]); uo.w = f2bs(o[3]);
    }
    *(ushort4*)(u + (size_t)bl * 256 + c4) = uo;

    float zm[4], zc[4], zp[4];
    cvt4(hasm ? *(const ushort4*)(r + c4 - 256) : zz, zm);
    cvt4(*(const ushort4*)(r + 256 + c4), zc);
    cvt4(hasp ? *(const ushort4*)(r + 768 + c4) : zz, zp);
    ushort4 zo;
    {
        float o[4];
        #pragma unroll
        for (int j = 0; j < 4; ++j) {
            int cch = c4 + j;
            float v = zm[j] * ldw(wz, 3*cch, wbf) + zc[j] * ldw(wz, 3*cch+1, wbf) + zp[j] * ldw(wz, 3*cch+2, wbf);
            o[j] = v / (1.f + __expf(-v));
        }
        zo.x = f2bs(o[0]); zo.y = f2bs(o[1]); zo.z = f2bs(o[2]); zo.w = f2bs(o[3]);
    }
    *(ushort4*)(z + (size_t)bl * 256 + c4) = zo;
}

// ------------------------------------------------- selective scan (chunked, DS-minimized)
__global__ __launch_bounds__(256) void scan_a_kernel(
    const unsigned short* __restrict__ delta, const unsigned short* __restrict__ u,
    const float* __restrict__ xdbl, const void* __restrict__ A_log,
    float* __restrict__ hend, float* __restrict__ dsum, const int* __restrict__ flagp)
{
    const bool wbf = (*flagp != 0);
    int blk = blockIdx.x;
    int b = blk / (NCH * 16);
    int rem = blk % (NCH * 16);
    int c = rem / 16, db = rem % 16;

    __shared__ unsigned int sdu[64][16];  // lo: delta, hi: u
    __shared__ float sB[64][16];

    const unsigned short* dp = delta + (size_t)b * L_ * 256;
    const unsigned short* up = u     + (size_t)b * L_ * 256;
    const float* xd = xdbl + (size_t)b * L_ * 48;

    int r = threadIdx.x >> 2, q = (threadIdx.x & 3) * 4;
    int lrow = c * 64 + r;
    {
        ushort4 dv = *(const ushort4*)(dp + (size_t)lrow * 256 + db * 16 + q);
        ushort4 uv = *(const ushort4*)(up + (size_t)lrow * 256 + db * 16 + q);
        uint4 pk;
        pk.x = (unsigned int)dv.x | ((unsigned int)uv.x << 16);
        pk.y = (unsigned int)dv.y | ((unsigned int)uv.y << 16);
        pk.z = (unsigned int)dv.z | ((unsigned int)uv.z << 16);
        pk.w = (unsigned int)dv.w | ((unsigned int)uv.w << 16);
        *(uint4*)&sdu[r][q] = pk;
        *(float4*)&sB[r][q] = *(const float4*)(xd + (size_t)lrow * 48 + 16 + q);
    }
    __syncthreads();

    int g = threadIdx.x >> 4, n = threadIdx.x & 15;
    int d = db * 16 + g;
    float An2 = -__expf(ldw(A_log, d * 16 + n, wbf)) * 1.44269504088896f;
    float h = 0.f, s = 0.f;
    #pragma unroll 8
    for (int t2 = 0; t2 < 64; ++t2) {
        unsigned int du = sdu[t2][g];
        float ds = __uint_as_float(du << 16);
        float ut = __uint_as_float(du & 0xFFFF0000u);
        float Bn = sB[t2][n];
        float e = exp2f(ds * An2);
        h = fmaf(e, h, ds * ut * Bn);
        s += ds;
    }
    size_t pair = (size_t)b * 256 + d;
    hend[(pair * NCH + c) * 16 + n] = h;
    if (n == 0) dsum[pair * NCH + c] = s;
}

__global__ __launch_bounds__(256) void scan_b_kernel(
    const void* __restrict__ A_log, float* __restrict__ hend,
    const float* __restrict__ dsum, const int* __restrict__ flagp)
{
    const bool wbf = (*flagp != 0);
    int gid = blockIdx.x * 256 + threadIdx.x;   // 16384
    int pair = gid >> 4, n = gid & 15;
    int d = pair & 255;
    float An = -__expf(ldw(A_log, d * 16 + n, wbf));
    float H = 0.f;
    #pragma unroll 7
    for (int c = 0; c < NCH; ++c) {
        size_t idx = ((size_t)pair * NCH + c) * 16 + n;
        float he = hend[idx];
        hend[idx] = H;
        H = __expf(An * dsum[(size_t)pair * NCH + c]) * H + he;
    }
}

__global__ __launch_bounds__(256) void scan_c_kernel(
    const unsigned short* __restrict__ delta, const unsigned short* __restrict__ u,
    const float* __restrict__ xdbl, const void* __restrict__ A_log,
    const void* __restrict__ Dp, const float* __restrict__ hinit,
    unsigned short* __restrict__ y, const int* __restrict__ flagp)
{
    const bool wbf = (*flagp != 0);
    int blk = blockIdx.x;
    int b = blk / (NCH * 16);
    int rem = blk % (NCH * 16);
    int c = rem / 16, db = rem % 16;

    __shared__ unsigned int sdu[64][16];     // lo: delta, hi: u  (4 KB)
    __shared__ float sBC[64][16][2];         // [t2][n][B,C]      (8 KB)
    __shared__ float syp[64][16][4];         // quad partials     (16 KB)
    __shared__ unsigned short sy[64][16];    // final bf16 y      (2 KB)

    const unsigned short* dp = delta + (size_t)b * L_ * 256;
    const unsigned short* up = u     + (size_t)b * L_ * 256;
    const float* xd = xdbl + (size_t)b * L_ * 48;

    int r = threadIdx.x >> 2, q = (threadIdx.x & 3) * 4;
    int lrow = c * 64 + r;
    {
        ushort4 dv = *(const ushort4*)(dp + (size_t)lrow * 256 + db * 16 + q);
        ushort4 uv = *(const ushort4*)(up + (size_t)lrow * 256 + db * 16 + q);
        uint4 pk;
        pk.x = (unsigned int)dv.x | ((unsigned int)uv.x << 16);
        pk.y = (unsigned int)dv.y | ((unsigned int)uv.y << 16);
        pk.z = (unsigned int)dv.z | ((unsigned int)uv.z << 16);
        pk.w = (unsigned int)dv.w | ((unsigned int)uv.w << 16);
        *(uint4*)&sdu[r][q] = pk;
        float4 Bv = *(const float4*)(xd + (size_t)lrow * 48 + 16 + q);
        float4 Cv = *(const float4*)(xd + (size_t)lrow * 48 + 32 + q);
        float2 p0; p0.x = Bv.x; p0.y = Cv.x; *(float2*)&sBC[r][q + 0][0] = p0;
        float2 p1; p1.x = Bv.y; p1.y = Cv.y; *(float2*)&sBC[r][q + 1][0] = p1;
        float2 p2; p2.x = Bv.z; p2.y = Cv.z; *(float2*)&sBC[r][q + 2][0] = p2;
        float2 p3; p3.x = Bv.w; p3.y = Cv.w; *(float2*)&sBC[r][q + 3][0] = p3;
    }
    __syncthreads();

    int g = threadIdx.x >> 4, n = threadIdx.x & 15;
    int d = db * 16 + g;
    float An2 = -__expf(ldw(A_log, d * 16 + n, wbf)) * 1.44269504088896f;
    size_t pair = (size_t)b * 256 + d;
    float h = hinit[(pair * NCH + c) * 16 + n];
    const bool wlane = ((n & 3) == 0);
    #pragma unroll 4
    for (int t2 = 0; t2 < 64; ++t2) {
        unsigned int du = sdu[t2][g];
        float ds = __uint_as_float(du << 16);
        float ut = __uint_as_float(du & 0xFFFF0000u);
        float2 bc = *(const float2*)&sBC[t2][n][0];
        float e = exp2f(ds * An2);
        h = fmaf(e, h, ds * ut * bc.x);
        float yp = h * bc.y;
        yp = dpp_add_xor1(yp);
        yp = dpp_add_xor2(yp);
        if (wlane) syp[t2][g][n >> 2] = yp;
    }
    __syncthreads();

    // phase 2: reduce 4 quad-partials per (t2,g), add u*D, convert
    #pragma unroll
    for (int cc = 0; cc < 4; ++cc) {
        int cell = threadIdx.x + cc * 256;
        int t2 = cell >> 4, gg = cell & 15;
        float4 p = *(const float4*)&syp[t2][gg][0];
        unsigned int du = sdu[t2][gg];
        float ut = __uint_as_float(du & 0xFFFF0000u);
        float Dd = ldw(Dp, db * 16 + gg, wbf);
        sy[t2][gg] = f2bs(p.x + p.y + p.z + p.w + ut * Dd);
    }
    __syncthreads();
    *(ushort4*)(y + ((size_t)b * L_ + c * 64 + r) * 256 + db * 16 + q) = *(ushort4*)&sy[r][q];
}

// ------------------------------------------------- launch
extern "C" void kernel_launch(void* const* d_in, const int* in_sizes, int n_in,
                              void* d_out, int out_size, void* d_ws, size_t ws_size,
                              hipStream_t stream) {
    const void* x         = d_in[0];
    const void* ln1_g     = d_in[1];
    const void* ln1_b     = d_in[2];
    const void* ln2_g     = d_in[3];
    const void* ln2_b     = d_in[4];
    const void* in_proj_w = d_in[5];
    const void* conv_x_w  = d_in[6];
    const void* conv_z_w  = d_in[7];
    const void* x_proj_w  = d_in[8];
    const void* dt_proj_w = d_in[9];
    const void* dt_proj_b = d_in[10];
    const void* A_log     = d_in[11];
    const void* Dp        = d_in[12];
    const void* out_proj_w= d_in[13];
    const void* mlp_w1    = d_in[14];
    const void* mlp_b1    = d_in[15];
    const void* mlp_w2    = d_in[16];
    const void* mlp_b2    = d_in[17];

    float* ws = (float*)d_ws;
    unsigned short* xz    = (unsigned short*)(ws);
    unsigned short* delta = (unsigned short*)(ws);
    unsigned short* yb    = (unsigned short*)(ws + 1605632);
    float*          xdbl  = ws + 3211264;
    float*          hend  = ws + 3813376;
    float*          dsum  = ws + 4616192;
    unsigned short* hmid  = (unsigned short*)(ws);
    unsigned short* ub    = (unsigned short*)(ws + 6422528);
    unsigned short* xres  = (unsigned short*)(ws + 6422528);
    unsigned short* xnb   = (unsigned short*)(ws + 8028160);
    int*            flag  = (int*)(ws + 9633792);

    dim3 blk(256);
    const int KNOSPLIT = 1 << 30;

    // 0. dtype detection -> flag
    detect_kernel<<<1, blk, 0, stream>>>((const unsigned int*)x, flag);

    // 1. LN1: x(dual) -> xn (bf16)
    ln_kernel<<<M_ / 4, blk, 0, stream>>>(x, -1, ln1_g, ln1_b, xnb, flag);

    // 2. in_proj (MFMA): xn (M,256) x W(512,256)^T -> xz (M,512) bf16
    mgemm_kernel<EPI_NONE><<<dim3(8, 196), blk, 0, stream>>>(
        xnb, nullptr, KNOSPLIT, in_proj_w, xz, 512, 256, 256, 512, nullptr, nullptr, nullptr, flag);

    // 3. conv+silu: xz -> u (bf16), z (bf16, overwrites xn)
    conv_silu_kernel<<<M_ / 4, blk, 0, stream>>>(xz, conv_x_w, conv_z_w, ub, xnb, flag);

    // 4. x_proj: u (M,256) x W(48,256)^T -> xdbl (M,48) fp32
    gemm_kernel<EPI_NONE, true, false><<<dim3(1, 98), blk, 0, stream>>>(
        ub, nullptr, 256, x_proj_w, xdbl, 48, 256, 256, 48, nullptr, nullptr, nullptr, flag);

    // 5. dt_proj + softplus: xdbl[:,:16] x W(256,16)^T -> delta (bf16)
    gemm_kernel<EPI_SP, false, true><<<dim3(2, 98), blk, 0, stream>>>(
        xdbl, nullptr, 16, dt_proj_w, delta, 256, 16, 48, 256, dt_proj_b, nullptr, nullptr, flag);

    // 6-8. selective scan
    scan_a_kernel<<<B_ * NCH * 16, blk, 0, stream>>>(delta, ub, xdbl, A_log, hend, dsum, flag);
    scan_b_kernel<<<64, blk, 0, stream>>>(A_log, hend, dsum, flag);
    scan_c_kernel<<<B_ * NCH * 16, blk, 0, stream>>>(delta, ub, xdbl, A_log, Dp, hend, yb, flag);

    // 9. out_proj + residual (MFMA, split A = [y | z]): -> xres bf16
    mgemm_kernel<EPI_RES><<<dim3(4, 196), blk, 0, stream>>>(
        yb, xnb, 256, out_proj_w, xres, 256, 512, 256, 256, nullptr, x, nullptr, flag);

    // 10. LN2: xres -> xn2 (bf16, overwrites z)
    ln_kernel<<<M_ / 4, blk, 0, stream>>>(xres, 1, ln2_g, ln2_b, xnb, flag);

    // 11. MLP1 + bias + GELU (MFMA): xn2 x W(1024,256)^T -> hmid bf16
    mgemm_kernel<EPI_GELU><<<dim3(16, 196), blk, 0, stream>>>(
        xnb, nullptr, KNOSPLIT, mlp_w1, hmid, 1024, 256, 256, 1024, mlp_b1, nullptr, nullptr, flag);

    // 12. MLP2 + bias + residual (MFMA) -> d_out (dtype per flag)
    mgemm_kernel<EPI_OUT><<<dim3(4, 196), blk, 0, stream>>>(
        hmid, nullptr, KNOSPLIT, mlp_w2, d_out, 256, 1024, 1024, 256, mlp_b2, nullptr, xres, flag);
}

// Round 5
// 297.161 us; speedup vs baseline: 2.6561x; 1.1891x over previous
//
#include <hip/hip_runtime.h>
#include <hip/hip_bf16.h>

#define B_ 4
#define L_ 3136
#define D_ 256
#define NCH 49     // 49 chunks * 64 = 3136
#define LCH 64
#define M_ (B_*L_)

__device__ __forceinline__ float bf2f(unsigned short u) {
    union { unsigned int i; float f; } v; v.i = ((unsigned int)u) << 16; return v.f;
}
__device__ __forceinline__ unsigned short f2bs(float f) {
    __hip_bfloat16 h = __float2bfloat16(f);
    return *(unsigned short*)&h;
}
// dual-dtype load for INPUT tensors (bf16 if flag, else fp32)
__device__ __forceinline__ float ldw(const void* p, size_t i, bool bf) {
    return bf ? bf2f(((const unsigned short*)p)[i]) : ((const float*)p)[i];
}
__device__ __forceinline__ void cvt4(ushort4 a, float* o) {
    o[0] = bf2f(a.x); o[1] = bf2f(a.y); o[2] = bf2f(a.z); o[3] = bf2f(a.w);
}
__device__ __forceinline__ void cvt8g(const unsigned short* p, bool v, float* o) {
    if (v) {
        ushort4 a = *(const ushort4*)p;
        ushort4 b = *(const ushort4*)(p + 4);
        cvt4(a, o); cvt4(b, o + 4);
    } else {
        #pragma unroll
        for (int i = 0; i < 8; ++i) o[i] = 0.f;
    }
}
// DPP cross-lane adds within quads (xor1 / xor2) -- pure VALU, no LDS pipe
__device__ __forceinline__ float dpp_add_xor1(float x) {
    int m = __builtin_amdgcn_update_dpp(0, __float_as_int(x), 0xB1, 0xF, 0xF, true);
    return x + __int_as_float(m);
}
__device__ __forceinline__ float dpp_add_xor2(float x) {
    int m = __builtin_amdgcn_update_dpp(0, __float_as_int(x), 0x4E, 0xF, 0xF, true);
    return x + __int_as_float(m);
}

// ------------------------------------------------- dtype detection
__global__ __launch_bounds__(256) void detect_kernel(
    const unsigned int* __restrict__ xw, int* __restrict__ flag)
{
    int t = threadIdx.x; int cnt = 0;
    for (int i = t; i < 2048; i += 256) {
        unsigned int lo = xw[i] & 0xFFFFu;
        unsigned int e = (lo >> 7) & 0xFFu;
        if (e >= 0x58u && e <= 0x97u) cnt++;
    }
    #pragma unroll
    for (int o = 32; o > 0; o >>= 1) cnt += __shfl_down(cnt, o);
    __shared__ int sred[4];
    if ((t & 63) == 0) sred[t >> 6] = cnt;
    __syncthreads();
    if (t == 0) flag[0] = (sred[0] + sred[1] + sred[2] + sred[3] > 1024) ? 1 : 0;
}

// ------------------------------------------------- LayerNorm (1 wave = 1 row, 4 elem/thread)
__global__ __launch_bounds__(256) void ln_kernel(
    const void* __restrict__ xin, int inmode,   // -1: dual via flag; 1: bf16
    const void* __restrict__ g, const void* __restrict__ bsh,
    unsigned short* __restrict__ out, const int* __restrict__ flagp)
{
    const bool wbf = (*flagp != 0);
    const bool inbf = (inmode < 0) ? wbf : true;
    int row = blockIdx.x * 4 + (threadIdx.x >> 6);
    int lane = threadIdx.x & 63;
    size_t idx = (size_t)row * 256 + lane * 4;
    float v[4];
    if (inbf) {
        ushort4 a = *(const ushort4*)((const unsigned short*)xin + idx);
        cvt4(a, v);
    } else {
        float4 a = *(const float4*)((const float*)xin + idx);
        v[0] = a.x; v[1] = a.y; v[2] = a.z; v[3] = a.w;
    }
    float s = v[0] + v[1] + v[2] + v[3];
    float s2 = v[0]*v[0] + v[1]*v[1] + v[2]*v[2] + v[3]*v[3];
    #pragma unroll
    for (int o = 32; o > 0; o >>= 1) { s += __shfl_xor(s, o); s2 += __shfl_xor(s2, o); }
    float mean = s * (1.f / 256.f);
    float var  = s2 * (1.f / 256.f) - mean * mean;
    float rs = rsqrtf(var + 1e-5f);
    ushort4 o;
    o.x = f2bs((v[0] - mean) * rs * ldw(g, lane*4+0, wbf) + ldw(bsh, lane*4+0, wbf));
    o.y = f2bs((v[1] - mean) * rs * ldw(g, lane*4+1, wbf) + ldw(bsh, lane*4+1, wbf));
    o.z = f2bs((v[2] - mean) * rs * ldw(g, lane*4+2, wbf) + ldw(bsh, lane*4+2, wbf));
    o.w = f2bs((v[3] - mean) * rs * ldw(g, lane*4+3, wbf) + ldw(bsh, lane*4+3, wbf));
    *(ushort4*)(out + idx) = o;
}

// ------------------------------------------------- epilogue tags
enum { EPI_NONE = 0, EPI_SP = 1, EPI_RES = 2, EPI_GELU = 3, EPI_OUT = 4 };

// ------------------------------------------------- MFMA bf16 GEMM (64x64x64, dbuf, XOR-swizzle)
typedef __attribute__((ext_vector_type(8))) short bf16x8;
typedef __attribute__((ext_vector_type(4))) float f32x4;

__device__ __forceinline__ void gload_lds16(const void* g, void* l) {
    __builtin_amdgcn_global_load_lds(
        (const __attribute__((address_space(1))) unsigned int*)g,
        (__attribute__((address_space(3))) unsigned int*)l, 16, 0, 0);
}

template<int EPI>
__global__ __launch_bounds__(256) void mgemm_kernel(
    const unsigned short* __restrict__ A, const unsigned short* __restrict__ A2, int Ksplit,
    const void* __restrict__ W, void* __restrict__ Cout,
    int N, int K, int lda, int ldc,
    const void* __restrict__ bias, const void* __restrict__ resb,
    const unsigned short* __restrict__ resf, const int* __restrict__ flagp)
{
    const bool wbf = (*flagp != 0);
    __shared__ unsigned short As[2][64][64];
    __shared__ unsigned short Ws[2][64][64];
    const int tid = threadIdx.x;

    // XCD-chunked block swizzle (all grids are %8 == 0)
    const int nwg = gridDim.x * gridDim.y;
    int bid = blockIdx.y * gridDim.x + blockIdx.x;
    int wgid = ((nwg & 7) == 0) ? ((bid & 7) * (nwg >> 3) + (bid >> 3)) : bid;
    const int bx = wgid % gridDim.x;
    const int by = wgid / gridDim.x;
    const int bm = by * 64, bn = bx * 64;

    const int l = tid & 63, wid = tid >> 6;
    const int wr = wid >> 1, wc = wid & 1;   // wave 32x32 quadrant
    const int lr = l & 15;                   // frag row/col
    const int lq = l >> 4;                   // 0..3: k-subgroup / C row group
    const int srow = tid >> 3;               // staging row 0..31
    const int sblk = ((tid & 7) ^ (srow & 7)) * 8;  // swizzled SOURCE elem offset
    const int dcol = (tid & 7) * 8;          // linear LDS dest elem offset

    f32x4 acc[2][2] = {};
    const int NT = K >> 6;

    auto stage = [&](int buf, int k0s) {
        const unsigned short* Ab; int kc;
        if (k0s < Ksplit) { Ab = A;  kc = k0s; }
        else              { Ab = A2; kc = k0s - Ksplit; }
        gload_lds16(Ab + (size_t)(bm + srow) * lda + kc + sblk,      &As[buf][srow][dcol]);
        gload_lds16(Ab + (size_t)(bm + 32 + srow) * lda + kc + sblk, &As[buf][32 + srow][dcol]);
        if (wbf) {
            const unsigned short* Wb = (const unsigned short*)W;
            gload_lds16(Wb + (size_t)(bn + srow) * K + k0s + sblk,      &Ws[buf][srow][dcol]);
            gload_lds16(Wb + (size_t)(bn + 32 + srow) * K + k0s + sblk, &Ws[buf][32 + srow][dcol]);
        } else {
            const float* Wf = (const float*)W;
            #pragma unroll
            for (int h = 0; h < 2; ++h) {
                int row = h * 32 + srow;
                const float* p = Wf + (size_t)(bn + row) * K + k0s + (tid & 7) * 8;
                float4 w0 = *(const float4*)p;
                float4 w1 = *(const float4*)(p + 4);
                ushort4 o0, o1;
                o0.x = f2bs(w0.x); o0.y = f2bs(w0.y); o0.z = f2bs(w0.z); o0.w = f2bs(w0.w);
                o1.x = f2bs(w1.x); o1.y = f2bs(w1.y); o1.z = f2bs(w1.z); o1.w = f2bs(w1.w);
                *(ushort4*)&Ws[buf][row][sblk]     = o0;
                *(ushort4*)&Ws[buf][row][sblk + 4] = o1;
            }
        }
    };

    stage(0, 0);
    asm volatile("s_waitcnt vmcnt(0)" ::: "memory");
    __syncthreads();

    int cur = 0;
    for (int kt = 0; kt < NT; ++kt) {
        if (kt + 1 < NT) stage(cur ^ 1, (kt + 1) << 6);

        bf16x8 af[2][2], bfr[2][2];
        #pragma unroll
        for (int i = 0; i < 2; ++i) {
            #pragma unroll
            for (int ks = 0; ks < 2; ++ks) {
                int ca = ((ks * 4 + lq) ^ (lr & 7)) * 8;   // swizzled read
                af[i][ks]  = *(const bf16x8*)&As[cur][wr * 32 + i * 16 + lr][ca];
                bfr[i][ks] = *(const bf16x8*)&Ws[cur][wc * 32 + i * 16 + lr][ca];
            }
        }
        #pragma unroll
        for (int ks = 0; ks < 2; ++ks)
            #pragma unroll
            for (int i = 0; i < 2; ++i)
                #pragma unroll
                for (int j = 0; j < 2; ++j)
                    acc[i][j] = __builtin_amdgcn_mfma_f32_16x16x32_bf16(af[i][ks], bfr[j][ks], acc[i][j], 0, 0, 0);

        if (kt + 1 < NT) {
            asm volatile("s_waitcnt vmcnt(0)" ::: "memory");
            __syncthreads();
            cur ^= 1;
        }
    }

    // epilogue: C frag: col = lr, row = lq*4 + e
    #pragma unroll
    for (int i = 0; i < 2; ++i) {
        #pragma unroll
        for (int j = 0; j < 2; ++j) {
            const int col = bn + wc * 32 + j * 16 + lr;
            #pragma unroll
            for (int e = 0; e < 4; ++e) {
                const int row = bm + wr * 32 + i * 16 + lq * 4 + e;
                float t = acc[i][j][e];
                if (EPI == EPI_RES) {
                    t += ldw(resb, (size_t)row * 256 + col, wbf);
                } else if (EPI == EPI_GELU) {
                    t += ldw(bias, col, wbf);
                    t = 0.5f * t * (1.f + erff(t * 0.70710678118654752f));
                } else if (EPI == EPI_OUT) {
                    t += ldw(bias, col, wbf) + bf2f(resf[(size_t)row * 256 + col]);
                }
                if (EPI == EPI_OUT && !wbf) {
                    ((float*)Cout)[(size_t)row * ldc + col] = t;
                } else {
                    ((unsigned short*)Cout)[(size_t)row * ldc + col] = f2bs(t);
                }
            }
        }
    }
}

// ------------------------------------------------- x_proj MFMA: u(M,256)bf16 x W(48,256)^T -> xdbl(M,48) fp32
__global__ __launch_bounds__(256) void xproj_kernel(
    const unsigned short* __restrict__ A, const void* __restrict__ W,
    float* __restrict__ Cout, const int* __restrict__ flagp)
{
    const bool wbf = (*flagp != 0);
    __shared__ unsigned short As[2][64][64];
    __shared__ unsigned short Ws[2][64][64];
    const int tid = threadIdx.x;
    const int bm = blockIdx.y * 64;   // gridDim.x == 1

    const int l = tid & 63, wid = tid >> 6;
    const int wr = wid >> 1, wc = wid & 1;
    const int lr = l & 15, lq = l >> 4;
    const int srow = tid >> 3;
    const int sblk = ((tid & 7) ^ (srow & 7)) * 8;
    const int dcol = (tid & 7) * 8;

    // zero W rows 48..63 of both buffers (stay zero across all K-tiles)
    {
        ushort4 zz4; zz4.x = 0; zz4.y = 0; zz4.z = 0; zz4.w = 0;
        int buf = tid >> 7, rr = 48 + ((tid >> 3) & 15), cc = (tid & 7) * 8;
        *(ushort4*)&Ws[buf][rr][cc] = zz4;
        *(ushort4*)&Ws[buf][rr][cc + 4] = zz4;
    }
    __syncthreads();

    f32x4 acc[2][2] = {};

    auto stage = [&](int buf, int k0s) {
        gload_lds16(A + (size_t)(bm + srow) * 256 + k0s + sblk,      &As[buf][srow][dcol]);
        gload_lds16(A + (size_t)(bm + 32 + srow) * 256 + k0s + sblk, &As[buf][32 + srow][dcol]);
        if (wbf) {
            const unsigned short* Wb = (const unsigned short*)W;
            gload_lds16(Wb + (size_t)srow * 256 + k0s + sblk, &Ws[buf][srow][dcol]);
            if (srow < 16)
                gload_lds16(Wb + (size_t)(32 + srow) * 256 + k0s + sblk, &Ws[buf][32 + srow][dcol]);
        } else {
            const float* Wf = (const float*)W;
            #pragma unroll
            for (int h = 0; h < 2; ++h) {
                int row = h * 32 + srow;
                if (row < 48) {
                    const float* p = Wf + (size_t)row * 256 + k0s + (tid & 7) * 8;
                    float4 w0 = *(const float4*)p;
                    float4 w1 = *(const float4*)(p + 4);
                    ushort4 o0, o1;
                    o0.x = f2bs(w0.x); o0.y = f2bs(w0.y); o0.z = f2bs(w0.z); o0.w = f2bs(w0.w);
                    o1.x = f2bs(w1.x); o1.y = f2bs(w1.y); o1.z = f2bs(w1.z); o1.w = f2bs(w1.w);
                    *(ushort4*)&Ws[buf][row][sblk]     = o0;
                    *(ushort4*)&Ws[buf][row][sblk + 4] = o1;
                }
            }
        }
    };

    stage(0, 0);
    asm volatile("s_waitcnt vmcnt(0)" ::: "memory");
    __syncthreads();

    int cur = 0;
    for (int kt = 0; kt < 4; ++kt) {
        if (kt + 1 < 4) stage(cur ^ 1, (kt + 1) << 6);
        bf16x8 af[2][2], bfr[2][2];
        #pragma unroll
        for (int i = 0; i < 2; ++i) {
            #pragma unroll
            for (int ks = 0; ks < 2; ++ks) {
                int ca = ((ks * 4 + lq) ^ (lr & 7)) * 8;
                af[i][ks]  = *(const bf16x8*)&As[cur][wr * 32 + i * 16 + lr][ca];
                bfr[i][ks] = *(const bf16x8*)&Ws[cur][wc * 32 + i * 16 + lr][ca];
            }
        }
        #pragma unroll
        for (int ks = 0; ks < 2; ++ks)
            #pragma unroll
            for (int i = 0; i < 2; ++i)
                #pragma unroll
                for (int j = 0; j < 2; ++j)
                    acc[i][j] = __builtin_amdgcn_mfma_f32_16x16x32_bf16(af[i][ks], bfr[j][ks], acc[i][j], 0, 0, 0);
        if (kt + 1 < 4) {
            asm volatile("s_waitcnt vmcnt(0)" ::: "memory");
            __syncthreads();
            cur ^= 1;
        }
    }

    #pragma unroll
    for (int i = 0; i < 2; ++i) {
        #pragma unroll
        for (int j = 0; j < 2; ++j) {
            const int col = wc * 32 + j * 16 + lr;
            if (col < 48) {
                #pragma unroll
                for (int e = 0; e < 4; ++e) {
                    const int row = bm + wr * 32 + i * 16 + lq * 4 + e;
                    Cout[(size_t)row * 48 + col] = acc[i][j][e];
                }
            }
        }
    }
}

// ------------------------------------------------- dt_proj MFMA (hi/lo split, K=16) + softplus
__global__ __launch_bounds__(256) void dtgemm_kernel(
    const float* __restrict__ Axd, const void* __restrict__ W,
    unsigned short* __restrict__ Cout, const void* __restrict__ bias,
    const int* __restrict__ flagp)
{
    const bool wbf = (*flagp != 0);
    __shared__ unsigned short Ah[64][16];
    __shared__ unsigned short Al[64][16];
    __shared__ unsigned short Wb[64][16];
    const int tid = threadIdx.x;
    const int nwg = gridDim.x * gridDim.y;
    int bid = blockIdx.y * gridDim.x + blockIdx.x;
    int wgid = ((nwg & 7) == 0) ? ((bid & 7) * (nwg >> 3) + (bid >> 3)) : bid;
    const int bx = wgid % gridDim.x, by = wgid / gridDim.x;
    const int bm = by * 64, bn = bx * 64;

    {
        int rr = tid >> 2, cc = (tid & 3) * 4;
        float4 v = *(const float4*)(Axd + (size_t)(bm + rr) * 48 + cc);
        float vv[4] = {v.x, v.y, v.z, v.w};
        ushort4 hi4, lo4;
        unsigned short* hp = (unsigned short*)&hi4;
        unsigned short* lp = (unsigned short*)&lo4;
        #pragma unroll
        for (int j = 0; j < 4; ++j) {
            unsigned short h = f2bs(vv[j]);
            hp[j] = h;
            lp[j] = f2bs(vv[j] - bf2f(h));
        }
        *(ushort4*)&Ah[rr][cc] = hi4;
        *(ushort4*)&Al[rr][cc] = lo4;
        // W rows bn..bn+63, 16 cols
        ushort4 wb4;
        unsigned short* wp = (unsigned short*)&wb4;
        if (wbf) {
            wb4 = *(const ushort4*)((const unsigned short*)W + (size_t)(bn + rr) * 16 + cc);
        } else {
            float4 wv = *(const float4*)((const float*)W + (size_t)(bn + rr) * 16 + cc);
            wp[0] = f2bs(wv.x); wp[1] = f2bs(wv.y); wp[2] = f2bs(wv.z); wp[3] = f2bs(wv.w);
        }
        *(ushort4*)&Wb[rr][cc] = wb4;
    }
    __syncthreads();

    const int l = tid & 63, wid = tid >> 6;
    const int wr = wid >> 1, wc = wid & 1;
    const int lr = l & 15, lq = l >> 4;

    f32x4 acc[2][2] = {};
    bf16x8 ah[2], al8[2], wb8[2];
    #pragma unroll
    for (int i = 0; i < 2; ++i) { ah[i] = bf16x8{}; al8[i] = bf16x8{}; wb8[i] = bf16x8{}; }
    if (lq < 2) {
        #pragma unroll
        for (int i = 0; i < 2; ++i) {
            ah[i]  = *(const bf16x8*)&Ah[wr * 32 + i * 16 + lr][lq * 8];
            al8[i] = *(const bf16x8*)&Al[wr * 32 + i * 16 + lr][lq * 8];
            wb8[i] = *(const bf16x8*)&Wb[wc * 32 + i * 16 + lr][lq * 8];
        }
    }
    #pragma unroll
    for (int i = 0; i < 2; ++i)
        #pragma unroll
        for (int j = 0; j < 2; ++j) {
            acc[i][j] = __builtin_amdgcn_mfma_f32_16x16x32_bf16(ah[i],  wb8[j], acc[i][j], 0, 0, 0);
            acc[i][j] = __builtin_amdgcn_mfma_f32_16x16x32_bf16(al8[i], wb8[j], acc[i][j], 0, 0, 0);
        }

    #pragma unroll
    for (int i = 0; i < 2; ++i) {
        #pragma unroll
        for (int j = 0; j < 2; ++j) {
            const int col = bn + wc * 32 + j * 16 + lr;
            #pragma unroll
            for (int e = 0; e < 4; ++e) {
                const int row = bm + wr * 32 + i * 16 + lq * 4 + e;
                float t = acc[i][j][e] + ldw(bias, col, wbf);
                t = (t > 20.f) ? t : log1pf(__expf(t));
                Cout[(size_t)row * 256 + col] = f2bs(t);
            }
        }
    }
}

// ------------------------------------------------- depthwise conv3 + SiLU (8 rows/block, 8 ch/thread, reg weights)
__global__ __launch_bounds__(256) void conv_silu_kernel(
    const unsigned short* __restrict__ xz,
    const void* __restrict__ wx, const void* __restrict__ wz,
    unsigned short* __restrict__ u, unsigned short* __restrict__ z,
    const int* __restrict__ flagp)
{
    const bool wbf = (*flagp != 0);
    int sub = threadIdx.x >> 5;          // 0..7 row within block
    int cb = (threadIdx.x & 31) * 8;     // channel base
    int bl = blockIdx.x * 8 + sub;
    int l = bl % L_;
    const unsigned short* r = xz + (size_t)bl * 512;
    bool hasm = (l > 0), hasp = (l < L_ - 1);

    // weights: wx[3*cb .. 3*cb+23] contiguous -> registers (vector loads)
    float wxa[24], wza[24];
    if (wbf) {
        const unsigned short* px = (const unsigned short*)wx + 3 * cb;
        const unsigned short* pz = (const unsigned short*)wz + 3 * cb;
        #pragma unroll
        for (int t = 0; t < 3; ++t) {
            cvt4(*(const ushort4*)(px + t * 8), &wxa[t * 8]);
            cvt4(*(const ushort4*)(px + t * 8 + 4), &wxa[t * 8 + 4]);
            cvt4(*(const ushort4*)(pz + t * 8), &wza[t * 8]);
            cvt4(*(const ushort4*)(pz + t * 8 + 4), &wza[t * 8 + 4]);
        }
    } else {
        const float* px = (const float*)wx + 3 * cb;
        const float* pz = (const float*)wz + 3 * cb;
        #pragma unroll
        for (int t = 0; t < 6; ++t) {
            *(float4*)&wxa[t * 4] = *(const float4*)(px + t * 4);
            *(float4*)&wza[t * 4] = *(const float4*)(pz + t * 4);
        }
    }

    float xm[8], xc[8], xp[8];
    // x path: channels cb..cb+7
    cvt8g(r + cb - 512, hasm, xm);
    cvt8g(r + cb,       true, xc);
    cvt8g(r + cb + 512, hasp, xp);
    ushort4 o0, o1;
    {
        unsigned short* op = (unsigned short*)&o0;
        unsigned short* op1 = (unsigned short*)&o1;
        #pragma unroll
        for (int j = 0; j < 8; ++j) {
            float v = xm[j] * wxa[3 * j] + xc[j] * wxa[3 * j + 1] + xp[j] * wxa[3 * j + 2];
            v = v / (1.f + __expf(-v));
            if (j < 4) op[j] = f2bs(v); else op1[j - 4] = f2bs(v);
        }
    }
    *(ushort4*)(u + (size_t)bl * 256 + cb) = o0;
    *(ushort4*)(u + (size_t)bl * 256 + cb + 4) = o1;

    // z path: channels 256+cb..
    cvt8g(r + cb - 256,  hasm, xm);
    cvt8g(r + 256 + cb,  true, xc);
    cvt8g(r + 768 + cb,  hasp, xp);
    {
        unsigned short* op = (unsigned short*)&o0;
        unsigned short* op1 = (unsigned short*)&o1;
        #pragma unroll
        for (int j = 0; j < 8; ++j) {
            float v = xm[j] * wza[3 * j] + xc[j] * wza[3 * j + 1] + xp[j] * wza[3 * j + 2];
            v = v / (1.f + __expf(-v));
            if (j < 4) op[j] = f2bs(v); else op1[j - 4] = f2bs(v);
        }
    }
    *(ushort4*)(z + (size_t)bl * 256 + cb) = o0;
    *(ushort4*)(z + (size_t)bl * 256 + cb + 4) = o1;
}

// ------------------------------------------------- selective scan (chunked, DS-minimized)
__global__ __launch_bounds__(256) void scan_a_kernel(
    const unsigned short* __restrict__ delta, const unsigned short* __restrict__ u,
    const float* __restrict__ xdbl, const void* __restrict__ A_log,
    float* __restrict__ hend, float* __restrict__ dsum, const int* __restrict__ flagp)
{
    const bool wbf = (*flagp != 0);
    int blk = blockIdx.x;
    int b = blk / (NCH * 16);
    int rem = blk % (NCH * 16);
    int c = rem / 16, db = rem % 16;

    __shared__ unsigned int sdu[64][16];  // lo: delta, hi: u
    __shared__ float sB[64][16];

    const unsigned short* dp = delta + (size_t)b * L_ * 256;
    const unsigned short* up = u     + (size_t)b * L_ * 256;
    const float* xd = xdbl + (size_t)b * L_ * 48;

    int r = threadIdx.x >> 2, q = (threadIdx.x & 3) * 4;
    int lrow = c * 64 + r;
    {
        ushort4 dv = *(const ushort4*)(dp + (size_t)lrow * 256 + db * 16 + q);
        ushort4 uv = *(const ushort4*)(up + (size_t)lrow * 256 + db * 16 + q);
        uint4 pk;
        pk.x = (unsigned int)dv.x | ((unsigned int)uv.x << 16);
        pk.y = (unsigned int)dv.y | ((unsigned int)uv.y << 16);
        pk.z = (unsigned int)dv.z | ((unsigned int)uv.z << 16);
        pk.w = (unsigned int)dv.w | ((unsigned int)uv.w << 16);
        *(uint4*)&sdu[r][q] = pk;
        *(float4*)&sB[r][q] = *(const float4*)(xd + (size_t)lrow * 48 + 16 + q);
    }
    __syncthreads();

    int g = threadIdx.x >> 4, n = threadIdx.x & 15;
    int d = db * 16 + g;
    float An2 = -__expf(ldw(A_log, d * 16 + n, wbf)) * 1.44269504088896f;
    float h = 0.f, s = 0.f;
    #pragma unroll 8
    for (int t2 = 0; t2 < 64; ++t2) {
        unsigned int du = sdu[t2][g];
        float ds = __uint_as_float(du << 16);
        float ut = __uint_as_float(du & 0xFFFF0000u);
        float Bn = sB[t2][n];
        float e = exp2f(ds * An2);
        h = fmaf(e, h, ds * ut * Bn);
        s += ds;
    }
    size_t pair = (size_t)b * 256 + d;
    hend[(pair * NCH + c) * 16 + n] = h;
    if (n == 0) dsum[pair * NCH + c] = s;
}

__global__ __launch_bounds__(256) void scan_b_kernel(
    const void* __restrict__ A_log, float* __restrict__ hend,
    const float* __restrict__ dsum, const int* __restrict__ flagp)
{
    const bool wbf = (*flagp != 0);
    int gid = blockIdx.x * 256 + threadIdx.x;   // 16384
    int pair = gid >> 4, n = gid & 15;
    int d = pair & 255;
    float An = -__expf(ldw(A_log, d * 16 + n, wbf));
    float H = 0.f;
    #pragma unroll 7
    for (int c = 0; c < NCH; ++c) {
        size_t idx = ((size_t)pair * NCH + c) * 16 + n;
        float he = hend[idx];
        hend[idx] = H;
        H = __expf(An * dsum[(size_t)pair * NCH + c]) * H + he;
    }
}

__global__ __launch_bounds__(256) void scan_c_kernel(
    const unsigned short* __restrict__ delta, const unsigned short* __restrict__ u,
    const float* __restrict__ xdbl, const void* __restrict__ A_log,
    const void* __restrict__ Dp, const float* __restrict__ hinit,
    unsigned short* __restrict__ y, const int* __restrict__ flagp)
{
    const bool wbf = (*flagp != 0);
    int blk = blockIdx.x;
    int b = blk / (NCH * 16);
    int rem = blk % (NCH * 16);
    int c = rem / 16, db = rem % 16;

    __shared__ unsigned int sdu[64][16];     // lo: delta, hi: u  (4 KB)
    __shared__ float sBC[64][16][2];         // [t2][n][B,C]      (8 KB)
    __shared__ float syp[64][16][4];         // quad partials     (16 KB)
    __shared__ unsigned short sy[64][16];    // final bf16 y      (2 KB)

    const unsigned short* dp = delta + (size_t)b * L_ * 256;
    const unsigned short* up = u     + (size_t)b * L_ * 256;
    const float* xd = xdbl + (size_t)b * L_ * 48;

    int r = threadIdx.x >> 2, q = (threadIdx.x & 3) * 4;
    int lrow = c * 64 + r;
    {
        ushort4 dv = *(const ushort4*)(dp + (size_t)lrow * 256 + db * 16 + q);
        ushort4 uv = *(const ushort4*)(up + (size_t)lrow * 256 + db * 16 + q);
        uint4 pk;
        pk.x = (unsigned int)dv.x | ((unsigned int)uv.x << 16);
        pk.y = (unsigned int)dv.y | ((unsigned int)uv.y << 16);
        pk.z = (unsigned int)dv.z | ((unsigned int)uv.z << 16);
        pk.w = (unsigned int)dv.w | ((unsigned int)uv.w << 16);
        *(uint4*)&sdu[r][q] = pk;
        float4 Bv = *(const float4*)(xd + (size_t)lrow * 48 + 16 + q);
        float4 Cv = *(const float4*)(xd + (size_t)lrow * 48 + 32 + q);
        float2 p0; p0.x = Bv.x; p0.y = Cv.x; *(float2*)&sBC[r][q + 0][0] = p0;
        float2 p1; p1.x = Bv.y; p1.y = Cv.y; *(float2*)&sBC[r][q + 1][0] = p1;
        float2 p2; p2.x = Bv.z; p2.y = Cv.z; *(float2*)&sBC[r][q + 2][0] = p2;
        float2 p3; p3.x = Bv.w; p3.y = Cv.w; *(float2*)&sBC[r][q + 3][0] = p3;
    }
    __syncthreads();

    int g = threadIdx.x >> 4, n = threadIdx.x & 15;
    int d = db * 16 + g;
    float An2 = -__expf(ldw(A_log, d * 16 + n, wbf)) * 1.44269504088896f;
    size_t pair = (size_t)b * 256 + d;
    float h = hinit[(pair * NCH + c) * 16 + n];
    const bool wlane = ((n & 3) == 0);
    #pragma unroll 4
    for (int t2 = 0; t2 < 64; ++t2) {
        unsigned int du = sdu[t2][g];
        float ds = __uint_as_float(du << 16);
        float ut = __uint_as_float(du & 0xFFFF0000u);
        float2 bc = *(const float2*)&sBC[t2][n][0];
        float e = exp2f(ds * An2);
        h = fmaf(e, h, ds * ut * bc.x);
        float yp = h * bc.y;
        yp = dpp_add_xor1(yp);
        yp = dpp_add_xor2(yp);
        if (wlane) syp[t2][g][n >> 2] = yp;
    }
    __syncthreads();

    // phase 2: reduce 4 quad-partials per (t2,g), add u*D, convert
    #pragma unroll
    for (int cc = 0; cc < 4; ++cc) {
        int cell = threadIdx.x + cc * 256;
        int t2 = cell >> 4, gg = cell & 15;
        float4 p = *(const float4*)&syp[t2][gg][0];
        unsigned int du = sdu[t2][gg];
        float ut = __uint_as_float(du & 0xFFFF0000u);
        float Dd = ldw(Dp, db * 16 + gg, wbf);
        sy[t2][gg] = f2bs(p.x + p.y + p.z + p.w + ut * Dd);
    }
    __syncthreads();
    *(ushort4*)(y + ((size_t)b * L_ + c * 64 + r) * 256 + db * 16 + q) = *(ushort4*)&sy[r][q];
}

// ------------------------------------------------- launch
extern "C" void kernel_launch(void* const* d_in, const int* in_sizes, int n_in,
                              void* d_out, int out_size, void* d_ws, size_t ws_size,
                              hipStream_t stream) {
    const void* x         = d_in[0];
    const void* ln1_g     = d_in[1];
    const void* ln1_b     = d_in[2];
    const void* ln2_g     = d_in[3];
    const void* ln2_b     = d_in[4];
    const void* in_proj_w = d_in[5];
    const void* conv_x_w  = d_in[6];
    const void* conv_z_w  = d_in[7];
    const void* x_proj_w  = d_in[8];
    const void* dt_proj_w = d_in[9];
    const void* dt_proj_b = d_in[10];
    const void* A_log     = d_in[11];
    const void* Dp        = d_in[12];
    const void* out_proj_w= d_in[13];
    const void* mlp_w1    = d_in[14];
    const void* mlp_b1    = d_in[15];
    const void* mlp_w2    = d_in[16];
    const void* mlp_b2    = d_in[17];

    float* ws = (float*)d_ws;
    unsigned short* xz    = (unsigned short*)(ws);
    unsigned short* delta = (unsigned short*)(ws);
    unsigned short* yb    = (unsigned short*)(ws + 1605632);
    float*          xdbl  = ws + 3211264;
    float*          hend  = ws + 3813376;
    float*          dsum  = ws + 4616192;
    unsigned short* hmid  = (unsigned short*)(ws);
    unsigned short* ub    = (unsigned short*)(ws + 6422528);
    unsigned short* xres  = (unsigned short*)(ws + 6422528);
    unsigned short* xnb   = (unsigned short*)(ws + 8028160);
    int*            flag  = (int*)(ws + 9633792);

    dim3 blk(256);
    const int KNOSPLIT = 1 << 30;

    // 0. dtype detection -> flag
    detect_kernel<<<1, blk, 0, stream>>>((const unsigned int*)x, flag);

    // 1. LN1: x(dual) -> xn (bf16)
    ln_kernel<<<M_ / 4, blk, 0, stream>>>(x, -1, ln1_g, ln1_b, xnb, flag);

    // 2. in_proj (MFMA): xn (M,256) x W(512,256)^T -> xz (M,512) bf16
    mgemm_kernel<EPI_NONE><<<dim3(8, 196), blk, 0, stream>>>(
        xnb, nullptr, KNOSPLIT, in_proj_w, xz, 512, 256, 256, 512, nullptr, nullptr, nullptr, flag);

    // 3. conv+silu: xz -> u (bf16), z (bf16, overwrites xn)
    conv_silu_kernel<<<M_ / 8, blk, 0, stream>>>(xz, conv_x_w, conv_z_w, ub, xnb, flag);

    // 4. x_proj (MFMA): u (M,256) x W(48,256)^T -> xdbl (M,48) fp32
    xproj_kernel<<<dim3(1, 196), blk, 0, stream>>>(ub, x_proj_w, xdbl, flag);

    // 5. dt_proj (MFMA hi/lo) + softplus: xdbl[:,:16] x W(256,16)^T -> delta (bf16)
    dtgemm_kernel<<<dim3(4, 196), blk, 0, stream>>>(xdbl, dt_proj_w, delta, dt_proj_b, flag);

    // 6-8. selective scan
    scan_a_kernel<<<B_ * NCH * 16, blk, 0, stream>>>(delta, ub, xdbl, A_log, hend, dsum, flag);
    scan_b_kernel<<<64, blk, 0, stream>>>(A_log, hend, dsum, flag);
    scan_c_kernel<<<B_ * NCH * 16, blk, 0, stream>>>(delta, ub, xdbl, A_log, Dp, hend, yb, flag);

    // 9. out_proj + residual (MFMA, split A = [y | z]): -> xres bf16
    mgemm_kernel<EPI_RES><<<dim3(4, 196), blk, 0, stream>>>(
        yb, xnb, 256, out_proj_w, xres, 256, 512, 256, 256, nullptr, x, nullptr, flag);

    // 10. LN2: xres -> xn2 (bf16, overwrites z)
    ln_kernel<<<M_ / 4, blk, 0, stream>>>(xres, 1, ln2_g, ln2_b, xnb, flag);

    // 11. MLP1 + bias + GELU (MFMA): xn2 x W(1024,256)^T -> hmid bf16
    mgemm_kernel<EPI_GELU><<<dim3(16, 196), blk, 0, stream>>>(
        xnb, nullptr, KNOSPLIT, mlp_w1, hmid, 1024, 256, 256, 1024, mlp_b1, nullptr, nullptr, flag);

    // 12. MLP2 + bias + residual (MFMA) -> d_out (dtype per flag)
    mgemm_kernel<EPI_OUT><<<dim3(4, 196), blk, 0, stream>>>(
        hmid, nullptr, KNOSPLIT, mlp_w2, d_out, 256, 1024, 1024, 256, mlp_b2, nullptr, xres, flag);
}